// Round 4
// baseline (596.473 us; speedup 1.0000x reference)
//
#include <hip/hip_runtime.h>
#include <hip/hip_bf16.h>

#define N_NODES 100000
#define N_EDGES 3200000
#define NFEAT 256
#define NHID 128
#define NCLASS 64
#define SCAN_B 1024
#define NB_SCAN ((N_NODES + SCAN_B - 1) / SCAN_B)   // 98
#define NVEC4 (N_EDGES / 4)                          // 800000
#define RANGE (N_NODES / 8)                          // 12500 nodes per group
#define NSL 64                                       // edge slices per group

typedef unsigned int uint32;
typedef unsigned short ushort16;

// hand-rolled bf16 (RNE) — intermediates only, finite values
static __device__ __forceinline__ float b2f(ushort16 u) {
    union { float f; uint32 i; } c; c.i = ((uint32)u) << 16; return c.f;
}
static __device__ __forceinline__ ushort16 f2b(float f) {
    union { float f; uint32 i; } c; c.f = f;
    uint32 r = (c.i + 0x7FFFu + ((c.i >> 16) & 1u)) >> 16;
    return (ushort16)r;
}
// unpack bf16 pair packed in a uint32 (little-endian: low ushort = even class)
static __device__ __forceinline__ float blo(uint32 u) {
    union { float f; uint32 i; } c; c.i = u << 16; return c.f;
}
static __device__ __forceinline__ float bhi(uint32 u) {
    union { float f; uint32 i; } c; c.i = u & 0xFFFF0000u; return c.f;
}

// ---------------- phase A: LDS-privatized histogram ----------------
__global__ __launch_bounds__(256) void k_hist(const int4* __restrict__ src4,
                                              const int4* __restrict__ dst4,
                                              uint32* __restrict__ scratch) {
    __shared__ uint32 h[RANGE];   // 50 KB
    int g = blockIdx.x & 7, sl = blockIdx.x >> 3;
    int lo = g * RANGE, hi = lo + RANGE;
    for (int i = threadIdx.x; i < RANGE; i += 256) h[i] = 0u;
    __syncthreads();
    for (int t = sl * 256 + threadIdx.x; t < NVEC4; t += NSL * 256) {
        int4 s = src4[t], d = dst4[t];
        if (s.x >= lo && s.x < hi) atomicAdd(&h[s.x - lo], 1u);
        if (s.y >= lo && s.y < hi) atomicAdd(&h[s.y - lo], 1u);
        if (s.z >= lo && s.z < hi) atomicAdd(&h[s.z - lo], 1u);
        if (s.w >= lo && s.w < hi) atomicAdd(&h[s.w - lo], 1u);
        if (d.x >= lo && d.x < hi) atomicAdd(&h[d.x - lo], 65536u);
        if (d.y >= lo && d.y < hi) atomicAdd(&h[d.y - lo], 65536u);
        if (d.z >= lo && d.z < hi) atomicAdd(&h[d.z - lo], 65536u);
        if (d.w >= lo && d.w < hi) atomicAdd(&h[d.w - lo], 65536u);
    }
    __syncthreads();
    uint32* dstp = scratch + ((size_t)(g * NSL + sl)) * RANGE;
    for (int i = threadIdx.x; i < RANGE; i += 256) dstp[i] = h[i];
}

// ---------------- reduce per-block counts -> degrees + norms ----------------
__global__ void k_sumdeg(const uint32* __restrict__ scratch, int* __restrict__ deg_in,
                         float* __restrict__ n_src, float* __restrict__ n_dst) {
    int i = blockIdx.x * blockDim.x + threadIdx.x;
    if (i >= N_NODES) return;
    int g = i / RANGE, r = i - g * RANGE;
    const uint32* base = scratch + (size_t)g * NSL * RANGE + r;
    uint32 so = 0, di = 0;
    for (int s = 0; s < NSL; s++) {
        uint32 v = base[(size_t)s * RANGE];
        so += v & 0xFFFFu;
        di += v >> 16;
    }
    deg_in[i] = (int)di;
    uint32 so1 = so < 1u ? 1u : so;
    uint32 di1 = di < 1u ? 1u : di;
    n_src[i] = rsqrtf((float)so1);
    n_dst[i] = rsqrtf((float)di1);
}

// ---------------- scan (3-pass) over deg_in -> row_ptr ----------------
__global__ void k_scan1(const int* __restrict__ deg_in, int* __restrict__ row_ptr,
                        int* __restrict__ blk_sums) {
    __shared__ int sh[SCAN_B];
    int i = blockIdx.x * SCAN_B + threadIdx.x;
    int v = (i < N_NODES) ? deg_in[i] : 0;
    sh[threadIdx.x] = v;
    __syncthreads();
    for (int o = 1; o < SCAN_B; o <<= 1) {
        int t = 0;
        if ((int)threadIdx.x >= o) t = sh[threadIdx.x - o];
        __syncthreads();
        sh[threadIdx.x] += t;
        __syncthreads();
    }
    if (i < N_NODES) row_ptr[i] = sh[threadIdx.x] - v;   // exclusive within block
    if (threadIdx.x == SCAN_B - 1) blk_sums[blockIdx.x] = sh[SCAN_B - 1];
}

__global__ void k_scan2(int* __restrict__ blk_sums) {
    if (threadIdx.x == 0 && blockIdx.x == 0) {
        int acc = 0;
        for (int b = 0; b < NB_SCAN; b++) { int v = blk_sums[b]; blk_sums[b] = acc; acc += v; }
        blk_sums[NB_SCAN] = acc;
    }
}

__global__ void k_scan3(const int* __restrict__ blk_sums, int* __restrict__ row_ptr) {
    int i = blockIdx.x * SCAN_B + threadIdx.x;
    if (i < N_NODES) row_ptr[i] += blk_sums[blockIdx.x];
    if (i == 0) row_ptr[N_NODES] = blk_sums[NB_SCAN];
}

// ---------------- per-(g,slice) cursor start offsets (in-place on scratch) ----------------
__global__ void k_offsets(uint32* __restrict__ scratch, const int* __restrict__ row_ptr) {
    int i = blockIdx.x * blockDim.x + threadIdx.x;
    if (i >= N_NODES) return;
    int g = i / RANGE, r = i - g * RANGE;
    uint32* base = scratch + (size_t)g * NSL * RANGE + r;
    uint32 run = (uint32)row_ptr[i];
    for (int s = 0; s < NSL; s++) {
        uint32 v = base[(size_t)s * RANGE];
        base[(size_t)s * RANGE] = run;
        run += v >> 16;
    }
}

// ---------------- phase B: atomic-free counting-sort fill ----------------
__global__ __launch_bounds__(256) void k_fill2(const int4* __restrict__ src4,
                                               const int4* __restrict__ dst4,
                                               const uint32* __restrict__ scratch,
                                               int* __restrict__ col) {
    __shared__ uint32 cur[RANGE];   // 50 KB
    int g = blockIdx.x & 7, sl = blockIdx.x >> 3;
    int lo = g * RANGE, hi = lo + RANGE;
    const uint32* base = scratch + ((size_t)(g * NSL + sl)) * RANGE;
    for (int i = threadIdx.x; i < RANGE; i += 256) cur[i] = base[i];
    __syncthreads();
    for (int t = sl * 256 + threadIdx.x; t < NVEC4; t += NSL * 256) {
        int4 s = src4[t], d = dst4[t];
        if (d.x >= lo && d.x < hi) { uint32 p = atomicAdd(&cur[d.x - lo], 1u); col[p] = s.x; }
        if (d.y >= lo && d.y < hi) { uint32 p = atomicAdd(&cur[d.y - lo], 1u); col[p] = s.y; }
        if (d.z >= lo && d.z < hi) { uint32 p = atomicAdd(&cur[d.z - lo], 1u); col[p] = s.z; }
        if (d.w >= lo && d.w < hi) { uint32 p = atomicAdd(&cur[d.w - lo], 1u); col[p] = s.w; }
    }
}

// ---------------- tiny weight-collapse GEMMs ----------------
__global__ void k_w01(const float* __restrict__ W0, const float* __restrict__ W1,
                      float* __restrict__ W01) {
    __shared__ float row[NHID];
    int r = blockIdx.x, c = threadIdx.x;   // 128 threads
    row[c] = W0[r * NHID + c];
    __syncthreads();
    float acc = 0.f;
    for (int k = 0; k < NHID; k++) acc += row[k] * W1[k * NHID + c];
    W01[r * NHID + c] = acc;
}

__global__ void k_wc(const float* __restrict__ W01, const float* __restrict__ W2,
                     float* __restrict__ Wc) {
    __shared__ float row[NHID];
    int r = blockIdx.x, c = threadIdx.x;   // 64 threads
    row[c] = W01[r * NHID + c];
    row[c + 64] = W01[r * NHID + c + 64];
    __syncthreads();
    float acc = 0.f;
    for (int k = 0; k < NHID; k++) acc += row[k] * W2[k * NCLASS + c];
    Wc[r * NCLASS + c] = acc;
}

// bv[0..63] = b0@W1@W2, bv[64..127] = b1@W2
__global__ void k_bv(const float* __restrict__ b0, const float* __restrict__ W1,
                     const float* __restrict__ b1, const float* __restrict__ W2,
                     float* __restrict__ bv) {
    __shared__ float tmp[NHID];
    int c = threadIdx.x;   // 64 threads
    for (int cc = c; cc < NHID; cc += 64) {
        float a = 0.f;
        for (int k = 0; k < NHID; k++) a += b0[k] * W1[k * NHID + cc];
        tmp[cc] = a;
    }
    __syncthreads();
    float a1 = 0.f, a2 = 0.f;
    for (int k = 0; k < NHID; k++) {
        float wv = W2[k * NCLASS + c];
        a1 += tmp[k] * wv;
        a2 += b1[k] * wv;
    }
    bv[c] = a1;
    bv[64 + c] = a2;
}

// ---------------- main GEMM: y = x @ Wc  [N,256]x[256,64], bf16 output ----------------
// Both operands from LDS: x double-buffered in 32-k steps (reg-staged, coalesced
// float4 loads issued at iteration top, ds_write after compute -> HBM latency
// hidden under 512 FMA/thread), weights in 32 KB halves. x tile padded [64][36]
// (144 B row stride, 16B-aligned) -> 2-way-free bank pattern on reads+writes.
// R1 lesson: broadcast global x loads expose latency (141 us); R2 lesson: even
// 5-block residency can't hide a depth-1 per-wave VMEM chain (97.8 us).
#define GBK 32
#define XPAD 36
static __device__ __forceinline__ void fma4(float4& a, float xs, const float4& wv) {
    a.x += xs * wv.x; a.y += xs * wv.y; a.z += xs * wv.z; a.w += xs * wv.w;
}
__global__ __launch_bounds__(256) void k_gemm_y(const float* __restrict__ x,
                                                const float* __restrict__ Wc,
                                                ushort16* __restrict__ y) {
    __shared__ float w_sh[128][NCLASS];      // 32 KB (half of Wc)
    __shared__ float x_sh[2][64][XPAD];      // 18 KB double-buffered x tile
    int tid = threadIdx.x;
    int tx = tid & 15, ty = tid >> 4;
    int rowTile = blockIdx.x * 64;
    int row0 = rowTile + ty * 4;
    int c0 = tx * 4;

    // staging map: thread -> (srow, 16B k-chunk); lanes 0..7 cover one 128 B row
    // segment contiguously -> fully coalesced global loads.
    int srow = tid >> 3;          // 0..31
    int skc  = tid & 7;           // 0..7
    const float* gs0 = x + (size_t)min(rowTile + srow, N_NODES - 1) * NFEAT + skc * 4;
    const float* gs1 = x + (size_t)min(rowTile + srow + 32, N_NODES - 1) * NFEAT + skc * 4;

    // stage W half 0 + x k-step 0
    {
        const float4* wsrc = (const float4*)Wc;
        float4* wdst = (float4*)&w_sh[0][0];
        for (int i = tid; i < 2048; i += 256) wdst[i] = wsrc[i];
        float4 s0 = *(const float4*)(gs0);
        float4 s1 = *(const float4*)(gs1);
        *(float4*)&x_sh[0][srow][skc * 4] = s0;
        *(float4*)&x_sh[0][srow + 32][skc * 4] = s1;
    }
    __syncthreads();

    float4 acc0 = {0, 0, 0, 0}, acc1 = {0, 0, 0, 0}, acc2 = {0, 0, 0, 0}, acc3 = {0, 0, 0, 0};

    for (int t = 0; t < 8; ++t) {
        int pb = t & 1;
        float4 n0, n1;
        if (t < 7) {   // issue next-step loads early; consumed after compute
            n0 = *(const float4*)(gs0 + (t + 1) * GBK);
            n1 = *(const float4*)(gs1 + (t + 1) * GBK);
        }
        int klbase = (t & 3) * GBK;   // k offset within current W half
#pragma unroll
        for (int kk = 0; kk < GBK; kk += 4) {
            int kl = klbase + kk;
            float4 w0 = *(const float4*)&w_sh[kl + 0][c0];
            float4 w1 = *(const float4*)&w_sh[kl + 1][c0];
            float4 w2 = *(const float4*)&w_sh[kl + 2][c0];
            float4 w3 = *(const float4*)&w_sh[kl + 3][c0];
            float4 xa = *(const float4*)&x_sh[pb][ty * 4 + 0][kk];
            float4 xb = *(const float4*)&x_sh[pb][ty * 4 + 1][kk];
            float4 xc = *(const float4*)&x_sh[pb][ty * 4 + 2][kk];
            float4 xd = *(const float4*)&x_sh[pb][ty * 4 + 3][kk];
            fma4(acc0, xa.x, w0); fma4(acc0, xa.y, w1); fma4(acc0, xa.z, w2); fma4(acc0, xa.w, w3);
            fma4(acc1, xb.x, w0); fma4(acc1, xb.y, w1); fma4(acc1, xb.z, w2); fma4(acc1, xb.w, w3);
            fma4(acc2, xc.x, w0); fma4(acc2, xc.y, w1); fma4(acc2, xc.z, w2); fma4(acc2, xc.w, w3);
            fma4(acc3, xd.x, w0); fma4(acc3, xd.y, w1); fma4(acc3, xd.z, w2); fma4(acc3, xd.w, w3);
        }
        if (t == 3) {   // switch to W half 1 (all waves past half-0 reads first)
            __syncthreads();
            const float4* wsrc = (const float4*)Wc + 2048;
            float4* wdst = (float4*)&w_sh[0][0];
            for (int i = tid; i < 2048; i += 256) wdst[i] = wsrc[i];
        }
        if (t < 7) {    // write next x tile (other buffer, safe: last read at t-1)
            *(float4*)&x_sh[pb ^ 1][srow][skc * 4] = n0;
            *(float4*)&x_sh[pb ^ 1][srow + 32][skc * 4] = n1;
        }
        __syncthreads();
    }

    ushort4 o0 = {f2b(acc0.x), f2b(acc0.y), f2b(acc0.z), f2b(acc0.w)};
    ushort4 o1 = {f2b(acc1.x), f2b(acc1.y), f2b(acc1.z), f2b(acc1.w)};
    ushort4 o2 = {f2b(acc2.x), f2b(acc2.y), f2b(acc2.z), f2b(acc2.w)};
    ushort4 o3 = {f2b(acc3.x), f2b(acc3.y), f2b(acc3.z), f2b(acc3.w)};
    if (row0 + 0 < N_NODES) *(ushort4*)(y + (size_t)(row0 + 0) * NCLASS + c0) = o0;
    if (row0 + 1 < N_NODES) *(ushort4*)(y + (size_t)(row0 + 1) * NCLASS + c0) = o1;
    if (row0 + 2 < N_NODES) *(ushort4*)(y + (size_t)(row0 + 2) * NCLASS + c0) = o2;
    if (row0 + 3 < N_NODES) *(ushort4*)(y + (size_t)(row0 + 3) * NCLASS + c0) = o3;
}

// ---------------- fused aggregation passes (8-edges-per-load gather) ----------------
// Wave layout: lane = g*8 + sub. Group g (8 lanes) handles edge slot g of each
// 32-edge chunk; lane loads dwordx4 = 8 bf16 classes [sub*8, sub*8+8) of row col[p].
// One feature-load instruction gathers 8 edges (1 KB/instr) vs 1 edge (128 B) before.
// End: butterfly over lane-XOR {8,16,32} sums the 8 edge-groups.
// PASS 1: out = Âin, tout = Â·1 ; PASS 2: out = Âin, tout = Â·tin
// PASS 3: outf = softmax(Âin + t2*bv0 + t1*bv1 + b2)  (f32 output)
template <int PASS>
__global__ __launch_bounds__(256) void k_agg(
        const int* __restrict__ row_ptr, const int* __restrict__ col,
        const float* __restrict__ n_src, const float* __restrict__ n_dst,
        const ushort16* __restrict__ in, ushort16* __restrict__ out,
        float* __restrict__ outf,
        const float* __restrict__ tin, float* __restrict__ tout,
        const float* __restrict__ t1, const float* __restrict__ t2,
        const float* __restrict__ bv, const float* __restrict__ b2) {
    int wid = threadIdx.x >> 6, lane = threadIdx.x & 63;
    int node = blockIdx.x * 4 + wid;
    if (node >= N_NODES) return;
    int g = lane >> 3, sub = lane & 7;
    int s = row_ptr[node], e = row_ptr[node + 1];
    const uint4* inr = (const uint4*)in;   // row j = 8 uint4s

    float acc0 = 0.f, acc1 = 0.f, acc2 = 0.f, acc3 = 0.f;
    float acc4 = 0.f, acc5 = 0.f, acc6 = 0.f, acc7 = 0.f;
    float accs = 0.f;

#define CH(P)                                                                  \
    {                                                                          \
        int p_ = (P);                                                          \
        bool v_ = p_ < e;                                                      \
        int j_ = v_ ? col[p_] : 0;                                             \
        float ns_ = n_src[j_];                                                 \
        if (!v_) ns_ = 0.f;                                                    \
        uint4 u_ = inr[(size_t)j_ * 8 + sub];                                  \
        acc0 += ns_ * blo(u_.x); acc1 += ns_ * bhi(u_.x);                      \
        acc2 += ns_ * blo(u_.y); acc3 += ns_ * bhi(u_.y);                      \
        acc4 += ns_ * blo(u_.z); acc5 += ns_ * bhi(u_.z);                      \
        acc6 += ns_ * blo(u_.w); acc7 += ns_ * bhi(u_.w);                      \
        if (PASS == 1) accs += ns_;                                            \
        if (PASS == 2) accs += ns_ * tin[j_];                                  \
    }

    for (int base = s; base < e; base += 32) {
        CH(base + g)
        CH(base + 8 + g)
        CH(base + 16 + g)
        CH(base + 24 + g)
    }
#undef CH

    // reduce across the 8 edge-groups (lane bits 3..5)
#pragma unroll
    for (int off = 8; off <= 32; off <<= 1) {
        acc0 += __shfl_xor(acc0, off, 64);
        acc1 += __shfl_xor(acc1, off, 64);
        acc2 += __shfl_xor(acc2, off, 64);
        acc3 += __shfl_xor(acc3, off, 64);
        acc4 += __shfl_xor(acc4, off, 64);
        acc5 += __shfl_xor(acc5, off, 64);
        acc6 += __shfl_xor(acc6, off, 64);
        acc7 += __shfl_xor(acc7, off, 64);
        if (PASS != 3) accs += __shfl_xor(accs, off, 64);
    }

    float nd = n_dst[node];
    if (PASS == 3) {
        float t2n = t2[node], t1n = t1[node];
        const float* bvA = bv + sub * 8;
        const float* bvB = bv + 64 + sub * 8;
        const float* b2p = b2 + sub * 8;
        float v0 = acc0 * nd + t2n * bvA[0] + t1n * bvB[0] + b2p[0];
        float v1 = acc1 * nd + t2n * bvA[1] + t1n * bvB[1] + b2p[1];
        float v2 = acc2 * nd + t2n * bvA[2] + t1n * bvB[2] + b2p[2];
        float v3 = acc3 * nd + t2n * bvA[3] + t1n * bvB[3] + b2p[3];
        float v4 = acc4 * nd + t2n * bvA[4] + t1n * bvB[4] + b2p[4];
        float v5 = acc5 * nd + t2n * bvA[5] + t1n * bvB[5] + b2p[5];
        float v6 = acc6 * nd + t2n * bvA[6] + t1n * bvB[6] + b2p[6];
        float v7 = acc7 * nd + t2n * bvA[7] + t1n * bvB[7] + b2p[7];
        float m = fmaxf(fmaxf(fmaxf(v0, v1), fmaxf(v2, v3)),
                        fmaxf(fmaxf(v4, v5), fmaxf(v6, v7)));
#pragma unroll
        for (int off = 1; off <= 4; off <<= 1) m = fmaxf(m, __shfl_xor(m, off, 64));
        float e0 = __expf(v0 - m), e1 = __expf(v1 - m), e2 = __expf(v2 - m), e3 = __expf(v3 - m);
        float e4 = __expf(v4 - m), e5 = __expf(v5 - m), e6 = __expf(v6 - m), e7 = __expf(v7 - m);
        float sum = ((e0 + e1) + (e2 + e3)) + ((e4 + e5) + (e6 + e7));
#pragma unroll
        for (int off = 1; off <= 4; off <<= 1) sum += __shfl_xor(sum, off, 64);
        float r = 1.0f / sum;
        if (g == 0) {
            float4 o0 = {e0 * r, e1 * r, e2 * r, e3 * r};
            float4 o1 = {e4 * r, e5 * r, e6 * r, e7 * r};
            float4* op = (float4*)(outf + (size_t)node * NCLASS + sub * 8);
            op[0] = o0;
            op[1] = o1;
        }
    } else {
        if (g == 0) {
            uint32 w0 = (uint32)f2b(acc0 * nd) | ((uint32)f2b(acc1 * nd) << 16);
            uint32 w1 = (uint32)f2b(acc2 * nd) | ((uint32)f2b(acc3 * nd) << 16);
            uint32 w2 = (uint32)f2b(acc4 * nd) | ((uint32)f2b(acc5 * nd) << 16);
            uint32 w3 = (uint32)f2b(acc6 * nd) | ((uint32)f2b(acc7 * nd) << 16);
            uint4 w = {w0, w1, w2, w3};
            *((uint4*)(out + (size_t)node * NCLASS) + sub) = w;
        }
        if (lane == 0) tout[node] = accs * nd;
    }
}

extern "C" void kernel_launch(void* const* d_in, const int* in_sizes, int n_in,
                              void* d_out, int out_size, void* d_ws, size_t ws_size,
                              hipStream_t stream) {
    const float* x   = (const float*)d_in[0];
    const int*   src = (const int*)d_in[1];
    const int*   dst = (const int*)d_in[2];
    const float* W0  = (const float*)d_in[3];
    const float* b0  = (const float*)d_in[4];
    const float* W1  = (const float*)d_in[5];
    const float* b1  = (const float*)d_in[6];
    const float* W2  = (const float*)d_in[7];
    const float* b2  = (const float*)d_in[8];
    float* out = (float*)d_out;

    size_t off = 0;
    auto alloc = [&](size_t bytes) {
        void* p = (char*)d_ws + off;
        off = (off + bytes + 255) & ~(size_t)255;
        return p;
    };
    int*      deg_in   = (int*)alloc(N_NODES * 4);
    float*    n_src    = (float*)alloc(N_NODES * 4);
    float*    n_dst    = (float*)alloc(N_NODES * 4);
    int*      row_ptr  = (int*)alloc((N_NODES + 1) * 4);
    int*      blk_sums = (int*)alloc((NB_SCAN + 1) * 4);
    int*      col      = (int*)alloc((size_t)N_EDGES * 4);
    uint32*   scratch  = (uint32*)alloc((size_t)8 * NSL * RANGE * 4);   // 25.6 MB
    float*    W01      = (float*)alloc(NFEAT * NHID * 4);
    float*    Wc       = (float*)alloc(NFEAT * NCLASS * 4);
    float*    bv       = (float*)alloc(128 * 4);
    float*    t1       = (float*)alloc(N_NODES * 4);
    float*    t2       = (float*)alloc(N_NODES * 4);
    ushort16* bufB1    = (ushort16*)alloc((size_t)N_NODES * NCLASS * 2);  // 12.8 MB bf16
    ushort16* bufB2    = (ushort16*)alloc((size_t)N_NODES * NCLASS * 2);  // 12.8 MB bf16
    (void)ws_size; (void)in_sizes; (void)n_in; (void)out_size;

    const int TB = 256;
    const int NBn = (N_NODES + TB - 1) / TB;
    const int NW = (N_NODES + 3) / 4;   // wave-per-node kernels
    const int GP = 8 * NSL;             // 512 blocks for hist/fill

    k_hist<<<GP, TB, 0, stream>>>((const int4*)src, (const int4*)dst, scratch);
    k_sumdeg<<<NBn, TB, 0, stream>>>(scratch, deg_in, n_src, n_dst);
    k_scan1<<<NB_SCAN, SCAN_B, 0, stream>>>(deg_in, row_ptr, blk_sums);
    k_scan2<<<1, 64, 0, stream>>>(blk_sums);
    k_scan3<<<NB_SCAN, SCAN_B, 0, stream>>>(blk_sums, row_ptr);
    k_offsets<<<NBn, TB, 0, stream>>>(scratch, row_ptr);
    k_fill2<<<GP, TB, 0, stream>>>((const int4*)src, (const int4*)dst, scratch, col);

    k_w01<<<NFEAT, NHID, 0, stream>>>(W0, W1, W01);
    k_wc<<<NFEAT, NCLASS, 0, stream>>>(W01, W2, Wc);
    k_bv<<<1, NCLASS, 0, stream>>>(b0, W1, b1, W2, bv);

    // Y -> B1 (bf16); Z1 -> B2 (+t1); Z2 -> B1 (+t2); pass3: B1 -> softmax -> OUT (f32)
    k_gemm_y<<<(N_NODES + 63) / 64, 256, 0, stream>>>(x, Wc, bufB1);

    k_agg<1><<<NW, 256, 0, stream>>>(row_ptr, col, n_src, n_dst, bufB1, bufB2, nullptr,
                                     nullptr, t1, nullptr, nullptr, nullptr, nullptr);
    k_agg<2><<<NW, 256, 0, stream>>>(row_ptr, col, n_src, n_dst, bufB2, bufB1, nullptr,
                                     t1, t2, nullptr, nullptr, nullptr, nullptr);
    k_agg<3><<<NW, 256, 0, stream>>>(row_ptr, col, n_src, n_dst, bufB1, nullptr, out,
                                     nullptr, nullptr, t1, t2, bv, b2);
}

// Round 6
// 538.954 us; speedup vs baseline: 1.1067x; 1.1067x over previous
//
#include <hip/hip_runtime.h>
#include <hip/hip_bf16.h>

#define N_NODES 100000
#define N_EDGES 3200000
#define NFEAT 256
#define NHID 128
#define NCLASS 64
#define SCAN_B 1024
#define NB_SCAN ((N_NODES + SCAN_B - 1) / SCAN_B)   // 98
#define NVEC4 (N_EDGES / 4)                          // 800000
#define RANGE (N_NODES / 8)                          // 12500 nodes per group
#define NSL 64                                       // edge slices per group

typedef unsigned int uint32;
typedef unsigned short ushort16;
typedef __attribute__((ext_vector_type(8))) short bf16x8;
typedef __attribute__((ext_vector_type(4))) float f32x4;

// hand-rolled bf16 (RNE) — intermediates only, finite values
static __device__ __forceinline__ float b2f(ushort16 u) {
    union { float f; uint32 i; } c; c.i = ((uint32)u) << 16; return c.f;
}
static __device__ __forceinline__ ushort16 f2b(float f) {
    union { float f; uint32 i; } c; c.f = f;
    uint32 r = (c.i + 0x7FFFu + ((c.i >> 16) & 1u)) >> 16;
    return (ushort16)r;
}
// unpack bf16 pair packed in a uint32 (little-endian: low ushort = even class)
static __device__ __forceinline__ float blo(uint32 u) {
    union { float f; uint32 i; } c; c.i = u << 16; return c.f;
}
static __device__ __forceinline__ float bhi(uint32 u) {
    union { float f; uint32 i; } c; c.i = u & 0xFFFF0000u; return c.f;
}

// ---------------- phase A: LDS-privatized histogram ----------------
__global__ __launch_bounds__(256) void k_hist(const int4* __restrict__ src4,
                                              const int4* __restrict__ dst4,
                                              uint32* __restrict__ scratch) {
    __shared__ uint32 h[RANGE];   // 50 KB
    int g = blockIdx.x & 7, sl = blockIdx.x >> 3;
    int lo = g * RANGE, hi = lo + RANGE;
    for (int i = threadIdx.x; i < RANGE; i += 256) h[i] = 0u;
    __syncthreads();
    for (int t = sl * 256 + threadIdx.x; t < NVEC4; t += NSL * 256) {
        int4 s = src4[t], d = dst4[t];
        if (s.x >= lo && s.x < hi) atomicAdd(&h[s.x - lo], 1u);
        if (s.y >= lo && s.y < hi) atomicAdd(&h[s.y - lo], 1u);
        if (s.z >= lo && s.z < hi) atomicAdd(&h[s.z - lo], 1u);
        if (s.w >= lo && s.w < hi) atomicAdd(&h[s.w - lo], 1u);
        if (d.x >= lo && d.x < hi) atomicAdd(&h[d.x - lo], 65536u);
        if (d.y >= lo && d.y < hi) atomicAdd(&h[d.y - lo], 65536u);
        if (d.z >= lo && d.z < hi) atomicAdd(&h[d.z - lo], 65536u);
        if (d.w >= lo && d.w < hi) atomicAdd(&h[d.w - lo], 65536u);
    }
    __syncthreads();
    uint32* dstp = scratch + ((size_t)(g * NSL + sl)) * RANGE;
    for (int i = threadIdx.x; i < RANGE; i += 256) dstp[i] = h[i];
}

// ---------------- reduce per-block counts -> degrees + norms ----------------
__global__ void k_sumdeg(const uint32* __restrict__ scratch, int* __restrict__ deg_in,
                         float* __restrict__ n_src, float* __restrict__ n_dst) {
    int i = blockIdx.x * blockDim.x + threadIdx.x;
    if (i >= N_NODES) return;
    int g = i / RANGE, r = i - g * RANGE;
    const uint32* base = scratch + (size_t)g * NSL * RANGE + r;
    uint32 so = 0, di = 0;
    for (int s = 0; s < NSL; s++) {
        uint32 v = base[(size_t)s * RANGE];
        so += v & 0xFFFFu;
        di += v >> 16;
    }
    deg_in[i] = (int)di;
    uint32 so1 = so < 1u ? 1u : so;
    uint32 di1 = di < 1u ? 1u : di;
    n_src[i] = rsqrtf((float)so1);
    n_dst[i] = rsqrtf((float)di1);
}

// ---------------- scan (3-pass) over deg_in -> row_ptr ----------------
__global__ void k_scan1(const int* __restrict__ deg_in, int* __restrict__ row_ptr,
                        int* __restrict__ blk_sums) {
    __shared__ int sh[SCAN_B];
    int i = blockIdx.x * SCAN_B + threadIdx.x;
    int v = (i < N_NODES) ? deg_in[i] : 0;
    sh[threadIdx.x] = v;
    __syncthreads();
    for (int o = 1; o < SCAN_B; o <<= 1) {
        int t = 0;
        if ((int)threadIdx.x >= o) t = sh[threadIdx.x - o];
        __syncthreads();
        sh[threadIdx.x] += t;
        __syncthreads();
    }
    if (i < N_NODES) row_ptr[i] = sh[threadIdx.x] - v;   // exclusive within block
    if (threadIdx.x == SCAN_B - 1) blk_sums[blockIdx.x] = sh[SCAN_B - 1];
}

__global__ void k_scan2(int* __restrict__ blk_sums) {
    if (threadIdx.x == 0 && blockIdx.x == 0) {
        int acc = 0;
        for (int b = 0; b < NB_SCAN; b++) { int v = blk_sums[b]; blk_sums[b] = acc; acc += v; }
        blk_sums[NB_SCAN] = acc;
    }
}

__global__ void k_scan3(const int* __restrict__ blk_sums, int* __restrict__ row_ptr) {
    int i = blockIdx.x * SCAN_B + threadIdx.x;
    if (i < N_NODES) row_ptr[i] += blk_sums[blockIdx.x];
    if (i == 0) row_ptr[N_NODES] = blk_sums[NB_SCAN];
}

// ---------------- per-(g,slice) cursor start offsets (in-place on scratch) ----------------
__global__ void k_offsets(uint32* __restrict__ scratch, const int* __restrict__ row_ptr) {
    int i = blockIdx.x * blockDim.x + threadIdx.x;
    if (i >= N_NODES) return;
    int g = i / RANGE, r = i - g * RANGE;
    uint32* base = scratch + (size_t)g * NSL * RANGE + r;
    uint32 run = (uint32)row_ptr[i];
    for (int s = 0; s < NSL; s++) {
        uint32 v = base[(size_t)s * RANGE];
        base[(size_t)s * RANGE] = run;
        run += v >> 16;
    }
}

// ---------------- phase B: atomic-free counting-sort fill ----------------
__global__ __launch_bounds__(256) void k_fill2(const int4* __restrict__ src4,
                                               const int4* __restrict__ dst4,
                                               const uint32* __restrict__ scratch,
                                               int* __restrict__ col) {
    __shared__ uint32 cur[RANGE];   // 50 KB
    int g = blockIdx.x & 7, sl = blockIdx.x >> 3;
    int lo = g * RANGE, hi = lo + RANGE;
    const uint32* base = scratch + ((size_t)(g * NSL + sl)) * RANGE;
    for (int i = threadIdx.x; i < RANGE; i += 256) cur[i] = base[i];
    __syncthreads();
    for (int t = sl * 256 + threadIdx.x; t < NVEC4; t += NSL * 256) {
        int4 s = src4[t], d = dst4[t];
        if (d.x >= lo && d.x < hi) { uint32 p = atomicAdd(&cur[d.x - lo], 1u); col[p] = s.x; }
        if (d.y >= lo && d.y < hi) { uint32 p = atomicAdd(&cur[d.y - lo], 1u); col[p] = s.y; }
        if (d.z >= lo && d.z < hi) { uint32 p = atomicAdd(&cur[d.z - lo], 1u); col[p] = s.z; }
        if (d.w >= lo && d.w < hi) { uint32 p = atomicAdd(&cur[d.w - lo], 1u); col[p] = s.w; }
    }
}

// ---------------- tiny weight-collapse GEMMs ----------------
__global__ void k_w01(const float* __restrict__ W0, const float* __restrict__ W1,
                      float* __restrict__ W01) {
    __shared__ float row[NHID];
    int r = blockIdx.x, c = threadIdx.x;   // 128 threads
    row[c] = W0[r * NHID + c];
    __syncthreads();
    float acc = 0.f;
    for (int k = 0; k < NHID; k++) acc += row[k] * W1[k * NHID + c];
    W01[r * NHID + c] = acc;
}

// also emits Wt: bf16, transposed [NCLASS][NFEAT] — B-operand for the MFMA GEMM
__global__ void k_wc(const float* __restrict__ W01, const float* __restrict__ W2,
                     float* __restrict__ Wc, ushort16* __restrict__ Wt) {
    __shared__ float row[NHID];
    int r = blockIdx.x, c = threadIdx.x;   // 64 threads
    row[c] = W01[r * NHID + c];
    row[c + 64] = W01[r * NHID + c + 64];
    __syncthreads();
    float acc = 0.f;
    for (int k = 0; k < NHID; k++) acc += row[k] * W2[k * NCLASS + c];
    Wc[r * NCLASS + c] = acc;
    Wt[(size_t)c * NFEAT + r] = f2b(acc);
}

// bv[0..63] = b0@W1@W2, bv[64..127] = b1@W2
__global__ void k_bv(const float* __restrict__ b0, const float* __restrict__ W1,
                     const float* __restrict__ b1, const float* __restrict__ W2,
                     float* __restrict__ bv) {
    __shared__ float tmp[NHID];
    int c = threadIdx.x;   // 64 threads
    for (int cc = c; cc < NHID; cc += 64) {
        float a = 0.f;
        for (int k = 0; k < NHID; k++) a += b0[k] * W1[k * NHID + cc];
        tmp[cc] = a;
    }
    __syncthreads();
    float a1 = 0.f, a2 = 0.f;
    for (int k = 0; k < NHID; k++) {
        float wv = W2[k * NCLASS + c];
        a1 += tmp[k] * wv;
        a2 += b1[k] * wv;
    }
    bv[c] = a1;
    bv[64 + c] = a2;
}

// ---------------- main GEMM: y = x @ Wc via MFMA, bf16 output ----------------
// R1-R3 lesson: f32 VALU path is latency/occupancy bound at best 97.8 us
// (VALU floor 21 us, MfmaUtil 0). Switch to v_mfma_f32_16x16x32_bf16:
// compute floor ~1.3 us -> pure HBM stream (~18 us). No LDS, no barriers.
// Wave owns 16 rows. A-frag: lane(l) = row l&15, k-group q=l>>4 holds
// x[row][kt*32+q*8 .. +8] -> two coalesced dwordx4 per k-step, all 16 issued
// up-front (deep VMEM pipeline), cvt to bf16 in-reg. B-frag from Wt (bf16,
// transposed, L1-hot): lane holds Wt[col][kt*32+q*8..+8] = one dwordx4.
// C/D (m89-verified): col=lane&15, row=(lane>>4)*4+reg.
__global__ __launch_bounds__(256) void k_gemm_y(const float* __restrict__ x,
                                                const ushort16* __restrict__ Wt,
                                                ushort16* __restrict__ y) {
    int tid = threadIdx.x;
    int wid = tid >> 6, lane = tid & 63;
    int q = lane >> 4, r = lane & 15;
    int rowbase = blockIdx.x * 64 + wid * 16;
    int rowld = min(rowbase + r, N_NODES - 1);
    const float* xp = x + (size_t)rowld * NFEAT + q * 8;

    // issue all A loads up-front (16 dwordx4 in flight per lane)
    float4 alo[8], ahi[8];
#pragma unroll
    for (int kt = 0; kt < 8; kt++) {
        alo[kt] = *(const float4*)(xp + kt * 32);
        ahi[kt] = *(const float4*)(xp + kt * 32 + 4);
    }

    f32x4 acc0 = {0.f, 0.f, 0.f, 0.f};
    f32x4 acc1 = {0.f, 0.f, 0.f, 0.f};
    f32x4 acc2 = {0.f, 0.f, 0.f, 0.f};
    f32x4 acc3 = {0.f, 0.f, 0.f, 0.f};

#pragma unroll
    for (int kt = 0; kt < 8; kt++) {
        bf16x8 af;
        af[0] = (short)f2b(alo[kt].x); af[1] = (short)f2b(alo[kt].y);
        af[2] = (short)f2b(alo[kt].z); af[3] = (short)f2b(alo[kt].w);
        af[4] = (short)f2b(ahi[kt].x); af[5] = (short)f2b(ahi[kt].y);
        af[6] = (short)f2b(ahi[kt].z); af[7] = (short)f2b(ahi[kt].w);
        const int ko = kt * 32 + q * 8;
        bf16x8 b0 = *(const bf16x8*)(Wt + (size_t)(0 * 16 + r) * NFEAT + ko);
        bf16x8 b1 = *(const bf16x8*)(Wt + (size_t)(1 * 16 + r) * NFEAT + ko);
        bf16x8 b2 = *(const bf16x8*)(Wt + (size_t)(2 * 16 + r) * NFEAT + ko);
        bf16x8 b3 = *(const bf16x8*)(Wt + (size_t)(3 * 16 + r) * NFEAT + ko);
        acc0 = __builtin_amdgcn_mfma_f32_16x16x32_bf16(af, b0, acc0, 0, 0, 0);
        acc1 = __builtin_amdgcn_mfma_f32_16x16x32_bf16(af, b1, acc1, 0, 0, 0);
        acc2 = __builtin_amdgcn_mfma_f32_16x16x32_bf16(af, b2, acc2, 0, 0, 0);
        acc3 = __builtin_amdgcn_mfma_f32_16x16x32_bf16(af, b3, acc3, 0, 0, 0);
    }

    int srow0 = rowbase + q * 4;
#pragma unroll
    for (int i = 0; i < 4; i++) {
        int rr = srow0 + i;
        if (rr < N_NODES) {
            ushort16* yp = y + (size_t)rr * NCLASS + r;
            yp[0]  = f2b(acc0[i]);
            yp[16] = f2b(acc1[i]);
            yp[32] = f2b(acc2[i]);
            yp[48] = f2b(acc3[i]);
        }
    }
}

// ---------------- fused aggregation passes (8-edges-per-load gather) ----------------
// Wave layout: lane = g*8 + sub. Group g (8 lanes) handles edge slot g of each
// 32-edge chunk; lane loads dwordx4 = 8 bf16 classes [sub*8, sub*8+8) of row col[p].
// One feature-load instruction gathers 8 edges (1 KB/instr) vs 1 edge (128 B) before.
// End: butterfly over lane-XOR {8,16,32} sums the 8 edge-groups.
// PASS 1: out = Âin, tout = Â·1 ; PASS 2: out = Âin, tout = Â·tin
// PASS 3: outf = softmax(Âin + t2*bv0 + t1*bv1 + b2)  (f32 output)
template <int PASS>
__global__ __launch_bounds__(256) void k_agg(
        const int* __restrict__ row_ptr, const int* __restrict__ col,
        const float* __restrict__ n_src, const float* __restrict__ n_dst,
        const ushort16* __restrict__ in, ushort16* __restrict__ out,
        float* __restrict__ outf,
        const float* __restrict__ tin, float* __restrict__ tout,
        const float* __restrict__ t1, const float* __restrict__ t2,
        const float* __restrict__ bv, const float* __restrict__ b2) {
    int wid = threadIdx.x >> 6, lane = threadIdx.x & 63;
    int node = blockIdx.x * 4 + wid;
    if (node >= N_NODES) return;
    int g = lane >> 3, sub = lane & 7;
    int s = row_ptr[node], e = row_ptr[node + 1];
    const uint4* inr = (const uint4*)in;   // row j = 8 uint4s

    float acc0 = 0.f, acc1 = 0.f, acc2 = 0.f, acc3 = 0.f;
    float acc4 = 0.f, acc5 = 0.f, acc6 = 0.f, acc7 = 0.f;
    float accs = 0.f;

#define CH(P)                                                                  \
    {                                                                          \
        int p_ = (P);                                                          \
        bool v_ = p_ < e;                                                      \
        int j_ = v_ ? col[p_] : 0;                                             \
        float ns_ = n_src[j_];                                                 \
        if (!v_) ns_ = 0.f;                                                    \
        uint4 u_ = inr[(size_t)j_ * 8 + sub];                                  \
        acc0 += ns_ * blo(u_.x); acc1 += ns_ * bhi(u_.x);                      \
        acc2 += ns_ * blo(u_.y); acc3 += ns_ * bhi(u_.y);                      \
        acc4 += ns_ * blo(u_.z); acc5 += ns_ * bhi(u_.z);                      \
        acc6 += ns_ * blo(u_.w); acc7 += ns_ * bhi(u_.w);                      \
        if (PASS == 1) accs += ns_;                                            \
        if (PASS == 2) accs += ns_ * tin[j_];                                  \
    }

    for (int base = s; base < e; base += 32) {
        CH(base + g)
        CH(base + 8 + g)
        CH(base + 16 + g)
        CH(base + 24 + g)
    }
#undef CH

    // reduce across the 8 edge-groups (lane bits 3..5)
#pragma unroll
    for (int off = 8; off <= 32; off <<= 1) {
        acc0 += __shfl_xor(acc0, off, 64);
        acc1 += __shfl_xor(acc1, off, 64);
        acc2 += __shfl_xor(acc2, off, 64);
        acc3 += __shfl_xor(acc3, off, 64);
        acc4 += __shfl_xor(acc4, off, 64);
        acc5 += __shfl_xor(acc5, off, 64);
        acc6 += __shfl_xor(acc6, off, 64);
        acc7 += __shfl_xor(acc7, off, 64);
        if (PASS != 3) accs += __shfl_xor(accs, off, 64);
    }

    float nd = n_dst[node];
    if (PASS == 3) {
        float t2n = t2[node], t1n = t1[node];
        const float* bvA = bv + sub * 8;
        const float* bvB = bv + 64 + sub * 8;
        const float* b2p = b2 + sub * 8;
        float v0 = acc0 * nd + t2n * bvA[0] + t1n * bvB[0] + b2p[0];
        float v1 = acc1 * nd + t2n * bvA[1] + t1n * bvB[1] + b2p[1];
        float v2 = acc2 * nd + t2n * bvA[2] + t1n * bvB[2] + b2p[2];
        float v3 = acc3 * nd + t2n * bvA[3] + t1n * bvB[3] + b2p[3];
        float v4 = acc4 * nd + t2n * bvA[4] + t1n * bvB[4] + b2p[4];
        float v5 = acc5 * nd + t2n * bvA[5] + t1n * bvB[5] + b2p[5];
        float v6 = acc6 * nd + t2n * bvA[6] + t1n * bvB[6] + b2p[6];
        float v7 = acc7 * nd + t2n * bvA[7] + t1n * bvB[7] + b2p[7];
        float m = fmaxf(fmaxf(fmaxf(v0, v1), fmaxf(v2, v3)),
                        fmaxf(fmaxf(v4, v5), fmaxf(v6, v7)));
#pragma unroll
        for (int off = 1; off <= 4; off <<= 1) m = fmaxf(m, __shfl_xor(m, off, 64));
        float e0 = __expf(v0 - m), e1 = __expf(v1 - m), e2 = __expf(v2 - m), e3 = __expf(v3 - m);
        float e4 = __expf(v4 - m), e5 = __expf(v5 - m), e6 = __expf(v6 - m), e7 = __expf(v7 - m);
        float sum = ((e0 + e1) + (e2 + e3)) + ((e4 + e5) + (e6 + e7));
#pragma unroll
        for (int off = 1; off <= 4; off <<= 1) sum += __shfl_xor(sum, off, 64);
        float r = 1.0f / sum;
        if (g == 0) {
            float4 o0 = {e0 * r, e1 * r, e2 * r, e3 * r};
            float4 o1 = {e4 * r, e5 * r, e6 * r, e7 * r};
            float4* op = (float4*)(outf + (size_t)node * NCLASS + sub * 8);
            op[0] = o0;
            op[1] = o1;
        }
    } else {
        if (g == 0) {
            uint32 w0 = (uint32)f2b(acc0 * nd) | ((uint32)f2b(acc1 * nd) << 16);
            uint32 w1 = (uint32)f2b(acc2 * nd) | ((uint32)f2b(acc3 * nd) << 16);
            uint32 w2 = (uint32)f2b(acc4 * nd) | ((uint32)f2b(acc5 * nd) << 16);
            uint32 w3 = (uint32)f2b(acc6 * nd) | ((uint32)f2b(acc7 * nd) << 16);
            uint4 w = {w0, w1, w2, w3};
            *((uint4*)(out + (size_t)node * NCLASS) + sub) = w;
        }
        if (lane == 0) tout[node] = accs * nd;
    }
}

extern "C" void kernel_launch(void* const* d_in, const int* in_sizes, int n_in,
                              void* d_out, int out_size, void* d_ws, size_t ws_size,
                              hipStream_t stream) {
    const float* x   = (const float*)d_in[0];
    const int*   src = (const int*)d_in[1];
    const int*   dst = (const int*)d_in[2];
    const float* W0  = (const float*)d_in[3];
    const float* b0  = (const float*)d_in[4];
    const float* W1  = (const float*)d_in[5];
    const float* b1  = (const float*)d_in[6];
    const float* W2  = (const float*)d_in[7];
    const float* b2  = (const float*)d_in[8];
    float* out = (float*)d_out;

    size_t off = 0;
    auto alloc = [&](size_t bytes) {
        void* p = (char*)d_ws + off;
        off = (off + bytes + 255) & ~(size_t)255;
        return p;
    };
    int*      deg_in   = (int*)alloc(N_NODES * 4);
    float*    n_src    = (float*)alloc(N_NODES * 4);
    float*    n_dst    = (float*)alloc(N_NODES * 4);
    int*      row_ptr  = (int*)alloc((N_NODES + 1) * 4);
    int*      blk_sums = (int*)alloc((NB_SCAN + 1) * 4);
    int*      col      = (int*)alloc((size_t)N_EDGES * 4);
    uint32*   scratch  = (uint32*)alloc((size_t)8 * NSL * RANGE * 4);   // 25.6 MB
    float*    W01      = (float*)alloc(NFEAT * NHID * 4);
    float*    Wc       = (float*)alloc(NFEAT * NCLASS * 4);
    ushort16* Wt       = (ushort16*)alloc((size_t)NFEAT * NCLASS * 2);  // bf16, transposed
    float*    bv       = (float*)alloc(128 * 4);
    float*    t1       = (float*)alloc(N_NODES * 4);
    float*    t2       = (float*)alloc(N_NODES * 4);
    ushort16* bufB1    = (ushort16*)alloc((size_t)N_NODES * NCLASS * 2);  // 12.8 MB bf16
    ushort16* bufB2    = (ushort16*)alloc((size_t)N_NODES * NCLASS * 2);  // 12.8 MB bf16
    (void)ws_size; (void)in_sizes; (void)n_in; (void)out_size;

    const int TB = 256;
    const int NBn = (N_NODES + TB - 1) / TB;
    const int NW = (N_NODES + 3) / 4;   // wave-per-node kernels
    const int GP = 8 * NSL;             // 512 blocks for hist/fill

    k_hist<<<GP, TB, 0, stream>>>((const int4*)src, (const int4*)dst, scratch);
    k_sumdeg<<<NBn, TB, 0, stream>>>(scratch, deg_in, n_src, n_dst);
    k_scan1<<<NB_SCAN, SCAN_B, 0, stream>>>(deg_in, row_ptr, blk_sums);
    k_scan2<<<1, 64, 0, stream>>>(blk_sums);
    k_scan3<<<NB_SCAN, SCAN_B, 0, stream>>>(blk_sums, row_ptr);
    k_offsets<<<NBn, TB, 0, stream>>>(scratch, row_ptr);
    k_fill2<<<GP, TB, 0, stream>>>((const int4*)src, (const int4*)dst, scratch, col);

    k_w01<<<NFEAT, NHID, 0, stream>>>(W0, W1, W01);
    k_wc<<<NFEAT, NCLASS, 0, stream>>>(W01, W2, Wc, Wt);
    k_bv<<<1, NCLASS, 0, stream>>>(b0, W1, b1, W2, bv);

    // Y -> B1 (bf16); Z1 -> B2 (+t1); Z2 -> B1 (+t2); pass3: B1 -> softmax -> OUT (f32)
    k_gemm_y<<<(N_NODES + 63) / 64, 256, 0, stream>>>(x, Wt, bufB1);

    k_agg<1><<<NW, 256, 0, stream>>>(row_ptr, col, n_src, n_dst, bufB1, bufB2, nullptr,
                                     nullptr, t1, nullptr, nullptr, nullptr, nullptr);
    k_agg<2><<<NW, 256, 0, stream>>>(row_ptr, col, n_src, n_dst, bufB2, bufB1, nullptr,
                                     t1, t2, nullptr, nullptr, nullptr, nullptr);
    k_agg<3><<<NW, 256, 0, stream>>>(row_ptr, col, n_src, n_dst, bufB1, nullptr, out,
                                     nullptr, nullptr, t1, t2, bv, b2);
}

// Round 7
// 535.607 us; speedup vs baseline: 1.1136x; 1.0062x over previous
//
#include <hip/hip_runtime.h>
#include <hip/hip_bf16.h>

#define N_NODES 100000
#define N_EDGES 3200000
#define NFEAT 256
#define NHID 128
#define NCLASS 64
#define SCAN_B 1024
#define NB_SCAN ((N_NODES + SCAN_B - 1) / SCAN_B)   // 98
#define NVEC4 (N_EDGES / 4)                          // 800000
#define RANGE (N_NODES / 8)                          // 12500 nodes per group
#define NSL 64                                       // edge slices per group

typedef unsigned int uint32;
typedef unsigned short ushort16;
typedef __attribute__((ext_vector_type(8))) short bf16x8;
typedef __attribute__((ext_vector_type(4))) float f32x4;
typedef __attribute__((ext_vector_type(2))) float f32x2;

// hand-rolled bf16 (RNE) — intermediates only, finite values
static __device__ __forceinline__ float b2f(ushort16 u) {
    union { float f; uint32 i; } c; c.i = ((uint32)u) << 16; return c.f;
}
static __device__ __forceinline__ ushort16 f2b(float f) {
    union { float f; uint32 i; } c; c.f = f;
    uint32 r = (c.i + 0x7FFFu + ((c.i >> 16) & 1u)) >> 16;
    return (ushort16)r;
}
// unpack bf16 pair packed in a uint32 (little-endian: low ushort = even class)
static __device__ __forceinline__ float blo(uint32 u) {
    union { float f; uint32 i; } c; c.i = u << 16; return c.f;
}
static __device__ __forceinline__ float bhi(uint32 u) {
    union { float f; uint32 i; } c; c.i = u & 0xFFFF0000u; return c.f;
}
static __device__ __forceinline__ uint32 pack2(float a, float b) {
    return (uint32)f2b(a) | ((uint32)f2b(b) << 16);
}

// ---------------- phase A: LDS-privatized histogram ----------------
__global__ __launch_bounds__(256) void k_hist(const int4* __restrict__ src4,
                                              const int4* __restrict__ dst4,
                                              uint32* __restrict__ scratch) {
    __shared__ uint32 h[RANGE];   // 50 KB
    int g = blockIdx.x & 7, sl = blockIdx.x >> 3;
    int lo = g * RANGE, hi = lo + RANGE;
    for (int i = threadIdx.x; i < RANGE; i += 256) h[i] = 0u;
    __syncthreads();
    for (int t = sl * 256 + threadIdx.x; t < NVEC4; t += NSL * 256) {
        int4 s = src4[t], d = dst4[t];
        if (s.x >= lo && s.x < hi) atomicAdd(&h[s.x - lo], 1u);
        if (s.y >= lo && s.y < hi) atomicAdd(&h[s.y - lo], 1u);
        if (s.z >= lo && s.z < hi) atomicAdd(&h[s.z - lo], 1u);
        if (s.w >= lo && s.w < hi) atomicAdd(&h[s.w - lo], 1u);
        if (d.x >= lo && d.x < hi) atomicAdd(&h[d.x - lo], 65536u);
        if (d.y >= lo && d.y < hi) atomicAdd(&h[d.y - lo], 65536u);
        if (d.z >= lo && d.z < hi) atomicAdd(&h[d.z - lo], 65536u);
        if (d.w >= lo && d.w < hi) atomicAdd(&h[d.w - lo], 65536u);
    }
    __syncthreads();
    uint32* dstp = scratch + ((size_t)(g * NSL + sl)) * RANGE;
    for (int i = threadIdx.x; i < RANGE; i += 256) dstp[i] = h[i];
}

// ---------------- reduce per-block counts -> degrees + norms ----------------
__global__ void k_sumdeg(const uint32* __restrict__ scratch, int* __restrict__ deg_in,
                         float* __restrict__ n_src, float* __restrict__ n_dst) {
    int i = blockIdx.x * blockDim.x + threadIdx.x;
    if (i >= N_NODES) return;
    if (i == 0) n_src[N_NODES] = 0.f;   // gather sentinel
    int g = i / RANGE, r = i - g * RANGE;
    const uint32* base = scratch + (size_t)g * NSL * RANGE + r;
    uint32 so = 0, di = 0;
    for (int s = 0; s < NSL; s++) {
        uint32 v = base[(size_t)s * RANGE];
        so += v & 0xFFFFu;
        di += v >> 16;
    }
    deg_in[i] = (int)di;
    uint32 so1 = so < 1u ? 1u : so;
    uint32 di1 = di < 1u ? 1u : di;
    n_src[i] = rsqrtf((float)so1);
    n_dst[i] = rsqrtf((float)di1);
}

// ---------------- scan (3-pass) over deg_in -> row_ptr ----------------
__global__ void k_scan1(const int* __restrict__ deg_in, int* __restrict__ row_ptr,
                        int* __restrict__ blk_sums) {
    __shared__ int sh[SCAN_B];
    int i = blockIdx.x * SCAN_B + threadIdx.x;
    int v = (i < N_NODES) ? deg_in[i] : 0;
    sh[threadIdx.x] = v;
    __syncthreads();
    for (int o = 1; o < SCAN_B; o <<= 1) {
        int t = 0;
        if ((int)threadIdx.x >= o) t = sh[threadIdx.x - o];
        __syncthreads();
        sh[threadIdx.x] += t;
        __syncthreads();
    }
    if (i < N_NODES) row_ptr[i] = sh[threadIdx.x] - v;   // exclusive within block
    if (threadIdx.x == SCAN_B - 1) blk_sums[blockIdx.x] = sh[SCAN_B - 1];
}

__global__ void k_scan2(int* __restrict__ blk_sums) {
    if (threadIdx.x == 0 && blockIdx.x == 0) {
        int acc = 0;
        for (int b = 0; b < NB_SCAN; b++) { int v = blk_sums[b]; blk_sums[b] = acc; acc += v; }
        blk_sums[NB_SCAN] = acc;
    }
}

__global__ void k_scan3(const int* __restrict__ blk_sums, int* __restrict__ row_ptr) {
    int i = blockIdx.x * SCAN_B + threadIdx.x;
    if (i < N_NODES) row_ptr[i] += blk_sums[blockIdx.x];
    if (i == 0) row_ptr[N_NODES] = blk_sums[NB_SCAN];
}

// ---------------- per-(g,slice) cursor start offsets (in-place on scratch) ----------------
__global__ void k_offsets(uint32* __restrict__ scratch, const int* __restrict__ row_ptr) {
    int i = blockIdx.x * blockDim.x + threadIdx.x;
    if (i >= N_NODES) return;
    int g = i / RANGE, r = i - g * RANGE;
    uint32* base = scratch + (size_t)g * NSL * RANGE + r;
    uint32 run = (uint32)row_ptr[i];
    for (int s = 0; s < NSL; s++) {
        uint32 v = base[(size_t)s * RANGE];
        base[(size_t)s * RANGE] = run;
        run += v >> 16;
    }
}

// ---------------- phase B: atomic-free counting-sort fill ----------------
__global__ __launch_bounds__(256) void k_fill2(const int4* __restrict__ src4,
                                               const int4* __restrict__ dst4,
                                               const uint32* __restrict__ scratch,
                                               int* __restrict__ col) {
    __shared__ uint32 cur[RANGE];   // 50 KB
    int g = blockIdx.x & 7, sl = blockIdx.x >> 3;
    int lo = g * RANGE, hi = lo + RANGE;
    const uint32* base = scratch + ((size_t)(g * NSL + sl)) * RANGE;
    for (int i = threadIdx.x; i < RANGE; i += 256) cur[i] = base[i];
    __syncthreads();
    for (int t = sl * 256 + threadIdx.x; t < NVEC4; t += NSL * 256) {
        int4 s = src4[t], d = dst4[t];
        if (d.x >= lo && d.x < hi) { uint32 p = atomicAdd(&cur[d.x - lo], 1u); col[p] = s.x; }
        if (d.y >= lo && d.y < hi) { uint32 p = atomicAdd(&cur[d.y - lo], 1u); col[p] = s.y; }
        if (d.z >= lo && d.z < hi) { uint32 p = atomicAdd(&cur[d.z - lo], 1u); col[p] = s.z; }
        if (d.w >= lo && d.w < hi) { uint32 p = atomicAdd(&cur[d.w - lo], 1u); col[p] = s.w; }
    }
}

// ---------------- tiny weight-collapse GEMMs ----------------
__global__ void k_w01(const float* __restrict__ W0, const float* __restrict__ W1,
                      float* __restrict__ W01) {
    __shared__ float row[NHID];
    int r = blockIdx.x, c = threadIdx.x;   // 128 threads
    row[c] = W0[r * NHID + c];
    __syncthreads();
    float acc = 0.f;
    for (int k = 0; k < NHID; k++) acc += row[k] * W1[k * NHID + c];
    W01[r * NHID + c] = acc;
}

// also emits Wt: bf16, transposed [NCLASS][NFEAT] — B-operand for the MFMA GEMM
__global__ void k_wc(const float* __restrict__ W01, const float* __restrict__ W2,
                     float* __restrict__ Wc, ushort16* __restrict__ Wt) {
    __shared__ float row[NHID];
    int r = blockIdx.x, c = threadIdx.x;   // 64 threads
    row[c] = W01[r * NHID + c];
    row[c + 64] = W01[r * NHID + c + 64];
    __syncthreads();
    float acc = 0.f;
    for (int k = 0; k < NHID; k++) acc += row[k] * W2[k * NCLASS + c];
    Wc[r * NCLASS + c] = acc;
    Wt[(size_t)c * NFEAT + r] = f2b(acc);
}

// bv[0..63] = b0@W1@W2, bv[64..127] = b1@W2
__global__ void k_bv(const float* __restrict__ b0, const float* __restrict__ W1,
                     const float* __restrict__ b1, const float* __restrict__ W2,
                     float* __restrict__ bv) {
    __shared__ float tmp[NHID];
    int c = threadIdx.x;   // 64 threads
    for (int cc = c; cc < NHID; cc += 64) {
        float a = 0.f;
        for (int k = 0; k < NHID; k++) a += b0[k] * W1[k * NHID + cc];
        tmp[cc] = a;
    }
    __syncthreads();
    float a1 = 0.f, a2 = 0.f;
    for (int k = 0; k < NHID; k++) {
        float wv = W2[k * NCLASS + c];
        a1 += tmp[k] * wv;
        a2 += b1[k] * wv;
    }
    bv[c] = a1;
    bv[64 + c] = a2;
}

// ---------------- main GEMM: ys = (x @ Wc) * n_src  via MFMA, bf16 ----------------
// Rows are pre-scaled by n_src[row] so the aggregation passes do pure adds
// (no per-edge n_src gather). Row N_NODES is a zeroed sentinel for invalid
// edge slots. C/D (m89-verified): col=lane&15, row=(lane>>4)*4+reg.
__global__ __launch_bounds__(256) void k_gemm_y(const float* __restrict__ x,
                                                const ushort16* __restrict__ Wt,
                                                const float* __restrict__ n_src,
                                                ushort16* __restrict__ y) {
    int tid = threadIdx.x;
    int wid = tid >> 6, lane = tid & 63;
    int q = lane >> 4, r = lane & 15;
    int rowbase = blockIdx.x * 64 + wid * 16;
    int rowld = min(rowbase + r, N_NODES - 1);
    const float* xp = x + (size_t)rowld * NFEAT + q * 8;

    // issue all A loads up-front (16 dwordx4 in flight per lane)
    float4 alo[8], ahi[8];
#pragma unroll
    for (int kt = 0; kt < 8; kt++) {
        alo[kt] = *(const float4*)(xp + kt * 32);
        ahi[kt] = *(const float4*)(xp + kt * 32 + 4);
    }

    f32x4 acc0 = {0.f, 0.f, 0.f, 0.f};
    f32x4 acc1 = {0.f, 0.f, 0.f, 0.f};
    f32x4 acc2 = {0.f, 0.f, 0.f, 0.f};
    f32x4 acc3 = {0.f, 0.f, 0.f, 0.f};

#pragma unroll
    for (int kt = 0; kt < 8; kt++) {
        bf16x8 af;
        af[0] = (short)f2b(alo[kt].x); af[1] = (short)f2b(alo[kt].y);
        af[2] = (short)f2b(alo[kt].z); af[3] = (short)f2b(alo[kt].w);
        af[4] = (short)f2b(ahi[kt].x); af[5] = (short)f2b(ahi[kt].y);
        af[6] = (short)f2b(ahi[kt].z); af[7] = (short)f2b(ahi[kt].w);
        const int ko = kt * 32 + q * 8;
        bf16x8 b0 = *(const bf16x8*)(Wt + (size_t)(0 * 16 + r) * NFEAT + ko);
        bf16x8 b1 = *(const bf16x8*)(Wt + (size_t)(1 * 16 + r) * NFEAT + ko);
        bf16x8 b2 = *(const bf16x8*)(Wt + (size_t)(2 * 16 + r) * NFEAT + ko);
        bf16x8 b3 = *(const bf16x8*)(Wt + (size_t)(3 * 16 + r) * NFEAT + ko);
        acc0 = __builtin_amdgcn_mfma_f32_16x16x32_bf16(af, b0, acc0, 0, 0, 0);
        acc1 = __builtin_amdgcn_mfma_f32_16x16x32_bf16(af, b1, acc1, 0, 0, 0);
        acc2 = __builtin_amdgcn_mfma_f32_16x16x32_bf16(af, b2, acc2, 0, 0, 0);
        acc3 = __builtin_amdgcn_mfma_f32_16x16x32_bf16(af, b3, acc3, 0, 0, 0);
    }

    int srow0 = rowbase + q * 4;
#pragma unroll
    for (int i = 0; i < 4; i++) {
        int rr = srow0 + i;
        if (rr < N_NODES) {
            float ns = n_src[rr];
            ushort16* yp = y + (size_t)rr * NCLASS + r;
            yp[0]  = f2b(acc0[i] * ns);
            yp[16] = f2b(acc1[i] * ns);
            yp[32] = f2b(acc2[i] * ns);
            yp[48] = f2b(acc3[i] * ns);
        } else if (rr == N_NODES) {   // zero sentinel row
            ushort16* yp = y + (size_t)rr * NCLASS + r;
            yp[0] = 0; yp[16] = 0; yp[32] = 0; yp[48] = 0;
        }
    }
}

// ---------------- fused aggregation passes (pre-scaled rows, pure-add) ----------------
// Rows in `in` are pre-scaled by n_src[src]; invalid edge slots map to the
// zeroed sentinel row N_NODES -> pure packed-f32 adds, no mask, no ns gather.
// wsrc (scalar gather, L2-resident, sentinel=0): PASS1 = n_src (t1 = Â·1);
// PASS2 = t1s = n_src*t1 (t2 = Â·t1). Outputs of PASS1/2 are re-scaled by
// n_src[node] for the next pass's gather.
// PASS3: outf = softmax(acc*nd + t2*bv0 + t1*bv1 + b2) (f32 output).
template <int PASS>
__global__ __launch_bounds__(256) void k_agg(
        const int* __restrict__ row_ptr, const int* __restrict__ col,
        const float* __restrict__ wsrc,
        const float* __restrict__ n_src, const float* __restrict__ n_dst,
        const ushort16* __restrict__ in, ushort16* __restrict__ out,
        float* __restrict__ outf,
        float* __restrict__ tsave, float* __restrict__ tssave,
        const float* __restrict__ t1, const float* __restrict__ t2,
        const float* __restrict__ bv, const float* __restrict__ b2) {
    int wid = threadIdx.x >> 6, lane = threadIdx.x & 63;
    int node = blockIdx.x * 4 + wid;
    if (node > N_NODES) return;
    int g = lane >> 3, sub = lane & 7;

    if (node == N_NODES) {   // write zero sentinel row for the next pass
        if (PASS != 3) {
            if (g == 0) {
                uint4 z = {0u, 0u, 0u, 0u};
                *((uint4*)((char*)out + ((size_t)N_NODES << 7)) + sub) = z;
            }
            if (lane == 0) {
                tsave[N_NODES] = 0.f;
                if (PASS == 1) tssave[N_NODES] = 0.f;
            }
        }
        return;
    }

    int s = row_ptr[node], e = row_ptr[node + 1];
    const char* inb = (const char*)in;
    const char* wb  = (const char*)wsrc;
    uint32 subo = (uint32)sub << 4;

    f32x2 a0 = {0.f, 0.f}, a1 = {0.f, 0.f}, a2 = {0.f, 0.f}, a3 = {0.f, 0.f};
    float accs = 0.f;

#define CH(P)                                                                  \
    {                                                                          \
        int p_ = (P);                                                          \
        bool v_ = p_ < e;                                                      \
        int j_ = v_ ? col[p_] : N_NODES;                                       \
        uint32 fo_ = ((uint32)j_ << 7) + subo;                                 \
        uint4 u_ = *(const uint4*)(inb + fo_);                                 \
        if (PASS != 3) accs += *(const float*)(wb + ((uint32)j_ << 2));        \
        f32x2 q0; q0.x = blo(u_.x); q0.y = bhi(u_.x);                          \
        f32x2 q1; q1.x = blo(u_.y); q1.y = bhi(u_.y);                          \
        f32x2 q2; q2.x = blo(u_.z); q2.y = bhi(u_.z);                          \
        f32x2 q3; q3.x = blo(u_.w); q3.y = bhi(u_.w);                          \
        a0 += q0; a1 += q1; a2 += q2; a3 += q3;                                \
    }

    for (int base = s; base < e; base += 32) {
        CH(base + g)
        CH(base + 8 + g)
        CH(base + 16 + g)
        CH(base + 24 + g)
    }
#undef CH

    // reduce across the 8 edge-groups (lane bits 3..5)
#pragma unroll
    for (int off = 8; off <= 32; off <<= 1) {
        a0.x += __shfl_xor(a0.x, off, 64); a0.y += __shfl_xor(a0.y, off, 64);
        a1.x += __shfl_xor(a1.x, off, 64); a1.y += __shfl_xor(a1.y, off, 64);
        a2.x += __shfl_xor(a2.x, off, 64); a2.y += __shfl_xor(a2.y, off, 64);
        a3.x += __shfl_xor(a3.x, off, 64); a3.y += __shfl_xor(a3.y, off, 64);
        if (PASS != 3) accs += __shfl_xor(accs, off, 64);
    }

    float nd = n_dst[node];
    if (PASS == 3) {
        float t2n = t2[node], t1n = t1[node];
        const float* bvA = bv + sub * 8;
        const float* bvB = bv + 64 + sub * 8;
        const float* b2p = b2 + sub * 8;
        float v0 = a0.x * nd + t2n * bvA[0] + t1n * bvB[0] + b2p[0];
        float v1 = a0.y * nd + t2n * bvA[1] + t1n * bvB[1] + b2p[1];
        float v2 = a1.x * nd + t2n * bvA[2] + t1n * bvB[2] + b2p[2];
        float v3 = a1.y * nd + t2n * bvA[3] + t1n * bvB[3] + b2p[3];
        float v4 = a2.x * nd + t2n * bvA[4] + t1n * bvB[4] + b2p[4];
        float v5 = a2.y * nd + t2n * bvA[5] + t1n * bvB[5] + b2p[5];
        float v6 = a3.x * nd + t2n * bvA[6] + t1n * bvB[6] + b2p[6];
        float v7 = a3.y * nd + t2n * bvA[7] + t1n * bvB[7] + b2p[7];
        float m = fmaxf(fmaxf(fmaxf(v0, v1), fmaxf(v2, v3)),
                        fmaxf(fmaxf(v4, v5), fmaxf(v6, v7)));
#pragma unroll
        for (int off = 1; off <= 4; off <<= 1) m = fmaxf(m, __shfl_xor(m, off, 64));
        float e0 = __expf(v0 - m), e1 = __expf(v1 - m), e2 = __expf(v2 - m), e3 = __expf(v3 - m);
        float e4 = __expf(v4 - m), e5 = __expf(v5 - m), e6 = __expf(v6 - m), e7 = __expf(v7 - m);
        float sum = ((e0 + e1) + (e2 + e3)) + ((e4 + e5) + (e6 + e7));
#pragma unroll
        for (int off = 1; off <= 4; off <<= 1) sum += __shfl_xor(sum, off, 64);
        float r = 1.0f / sum;
        if (g == 0) {
            float4 o0 = {e0 * r, e1 * r, e2 * r, e3 * r};
            float4 o1 = {e4 * r, e5 * r, e6 * r, e7 * r};
            float4* op = (float4*)(outf + (size_t)node * NCLASS + sub * 8);
            op[0] = o0;
            op[1] = o1;
        }
    } else {
        if (g == 0) {
            float sc = nd * n_src[node];   // pre-scale for the next pass's gather
            uint32 w0 = pack2(a0.x * sc, a0.y * sc);
            uint32 w1 = pack2(a1.x * sc, a1.y * sc);
            uint32 w2 = pack2(a2.x * sc, a2.y * sc);
            uint32 w3 = pack2(a3.x * sc, a3.y * sc);
            uint4 w = {w0, w1, w2, w3};
            *((uint4*)((char*)out + ((size_t)node << 7)) + sub) = w;
        }
        if (lane == 0) {
            float T = accs * nd;
            tsave[node] = T;
            if (PASS == 1) tssave[node] = T * n_src[node];
        }
    }
}

extern "C" void kernel_launch(void* const* d_in, const int* in_sizes, int n_in,
                              void* d_out, int out_size, void* d_ws, size_t ws_size,
                              hipStream_t stream) {
    const float* x   = (const float*)d_in[0];
    const int*   src = (const int*)d_in[1];
    const int*   dst = (const int*)d_in[2];
    const float* W0  = (const float*)d_in[3];
    const float* b0  = (const float*)d_in[4];
    const float* W1  = (const float*)d_in[5];
    const float* b1  = (const float*)d_in[6];
    const float* W2  = (const float*)d_in[7];
    const float* b2  = (const float*)d_in[8];
    float* out = (float*)d_out;

    size_t off = 0;
    auto alloc = [&](size_t bytes) {
        void* p = (char*)d_ws + off;
        off = (off + bytes + 255) & ~(size_t)255;
        return p;
    };
    int*      deg_in   = (int*)alloc(N_NODES * 4);
    float*    n_src    = (float*)alloc((N_NODES + 1) * 4);   // +1 sentinel (=0)
    float*    n_dst    = (float*)alloc(N_NODES * 4);
    int*      row_ptr  = (int*)alloc((N_NODES + 1) * 4);
    int*      blk_sums = (int*)alloc((NB_SCAN + 1) * 4);
    int*      col      = (int*)alloc((size_t)N_EDGES * 4);
    uint32*   scratch  = (uint32*)alloc((size_t)8 * NSL * RANGE * 4);   // 25.6 MB
    float*    W01      = (float*)alloc(NFEAT * NHID * 4);
    float*    Wc       = (float*)alloc(NFEAT * NCLASS * 4);
    ushort16* Wt       = (ushort16*)alloc((size_t)NFEAT * NCLASS * 2);  // bf16, transposed
    float*    bv       = (float*)alloc(128 * 4);
    float*    t1       = (float*)alloc((N_NODES + 1) * 4);
    float*    t1s      = (float*)alloc((N_NODES + 1) * 4);   // n_src*t1, sentinel=0
    float*    t2       = (float*)alloc((N_NODES + 1) * 4);
    ushort16* bufB1    = (ushort16*)alloc((size_t)(N_NODES + 1) * NCLASS * 2);  // +sentinel row
    ushort16* bufB2    = (ushort16*)alloc((size_t)(N_NODES + 1) * NCLASS * 2);
    (void)ws_size; (void)in_sizes; (void)n_in; (void)out_size;

    const int TB = 256;
    const int NBn = (N_NODES + TB - 1) / TB;
    const int NW = (N_NODES + 3) / 4 + 1;   // +1 block: sentinel-row writer
    const int GP = 8 * NSL;                 // 512 blocks for hist/fill

    k_hist<<<GP, TB, 0, stream>>>((const int4*)src, (const int4*)dst, scratch);
    k_sumdeg<<<NBn, TB, 0, stream>>>(scratch, deg_in, n_src, n_dst);
    k_scan1<<<NB_SCAN, SCAN_B, 0, stream>>>(deg_in, row_ptr, blk_sums);
    k_scan2<<<1, 64, 0, stream>>>(blk_sums);
    k_scan3<<<NB_SCAN, SCAN_B, 0, stream>>>(blk_sums, row_ptr);
    k_offsets<<<NBn, TB, 0, stream>>>(scratch, row_ptr);
    k_fill2<<<GP, TB, 0, stream>>>((const int4*)src, (const int4*)dst, scratch, col);

    k_w01<<<NFEAT, NHID, 0, stream>>>(W0, W1, W01);
    k_wc<<<NFEAT, NCLASS, 0, stream>>>(W01, W2, Wc, Wt);
    k_bv<<<1, NCLASS, 0, stream>>>(b0, W1, b1, W2, bv);

    // ys -> B1 (bf16, pre-scaled); Z1s -> B2 (+t1,t1s); Z2s -> B1 (+t2);
    // pass3: B1 -> softmax -> OUT (f32)
    k_gemm_y<<<(N_NODES + 64) / 64, 256, 0, stream>>>(x, Wt, n_src, bufB1);

    k_agg<1><<<NW, 256, 0, stream>>>(row_ptr, col, n_src, n_src, n_dst, bufB1, bufB2,
                                     nullptr, t1, t1s, nullptr, nullptr, nullptr, nullptr);
    k_agg<2><<<NW, 256, 0, stream>>>(row_ptr, col, t1s, n_src, n_dst, bufB2, bufB1,
                                     nullptr, t2, nullptr, nullptr, nullptr, nullptr, nullptr);
    k_agg<3><<<NW, 256, 0, stream>>>(row_ptr, col, nullptr, n_src, n_dst, bufB1, nullptr,
                                     out, nullptr, nullptr, t1, t2, bv, b2);
}

// Round 8
// 520.097 us; speedup vs baseline: 1.1468x; 1.0298x over previous
//
#include <hip/hip_runtime.h>
#include <hip/hip_bf16.h>

#define N_NODES 100000
#define N_EDGES 3200000
#define NFEAT 256
#define NHID 128
#define NCLASS 64
#define SCAN_B 1024
#define NB_SCAN ((N_NODES + SCAN_B - 1) / SCAN_B)   // 98
#define NVEC4 (N_EDGES / 4)                          // 800000
#define RANGE (N_NODES / 8)                          // 12500 nodes per group
#define NSL 64                                       // edge slices per group

typedef unsigned int uint32;
typedef unsigned short ushort16;
typedef __attribute__((ext_vector_type(8))) short bf16x8;
typedef __attribute__((ext_vector_type(4))) float f32x4;
typedef __attribute__((ext_vector_type(2))) float f32x2;

// hand-rolled bf16 (RNE) — intermediates only, finite values
static __device__ __forceinline__ float b2f(ushort16 u) {
    union { float f; uint32 i; } c; c.i = ((uint32)u) << 16; return c.f;
}
static __device__ __forceinline__ ushort16 f2b(float f) {
    union { float f; uint32 i; } c; c.f = f;
    uint32 r = (c.i + 0x7FFFu + ((c.i >> 16) & 1u)) >> 16;
    return (ushort16)r;
}
// unpack bf16 pair packed in a uint32 (little-endian: low ushort = even class)
static __device__ __forceinline__ float blo(uint32 u) {
    union { float f; uint32 i; } c; c.i = u << 16; return c.f;
}
static __device__ __forceinline__ float bhi(uint32 u) {
    union { float f; uint32 i; } c; c.i = u & 0xFFFF0000u; return c.f;
}
static __device__ __forceinline__ uint32 pack2(float a, float b) {
    return (uint32)f2b(a) | ((uint32)f2b(b) << 16);
}

// ---------------- phase A: LDS-privatized histogram ----------------
// 2 node-groups per block (100 KB LDS, 512 threads): each slice of the edge
// stream is read by 4 blocks instead of 8 -> 102 MB total reads (was 205 MB).
// Slice mapping (512-thread stride NSL*512) is IDENTICAL in k_fill2 so the
// per-(g,sl) counts match the fill cursors exactly.
__global__ __launch_bounds__(512) void k_hist(const int4* __restrict__ src4,
                                              const int4* __restrict__ dst4,
                                              uint32* __restrict__ scratch) {
    __shared__ uint32 h[2 * RANGE];   // 100 KB
    int gp = blockIdx.x & 3, sl = blockIdx.x >> 2;   // gp 0..3, sl 0..63
    int lo = gp * 2 * RANGE, hi = lo + 2 * RANGE;
    for (int i = threadIdx.x; i < 2 * RANGE; i += 512) h[i] = 0u;
    __syncthreads();
    for (int t = sl * 512 + threadIdx.x; t < NVEC4; t += NSL * 512) {
        int4 s = src4[t], d = dst4[t];
        if (s.x >= lo && s.x < hi) atomicAdd(&h[s.x - lo], 1u);
        if (s.y >= lo && s.y < hi) atomicAdd(&h[s.y - lo], 1u);
        if (s.z >= lo && s.z < hi) atomicAdd(&h[s.z - lo], 1u);
        if (s.w >= lo && s.w < hi) atomicAdd(&h[s.w - lo], 1u);
        if (d.x >= lo && d.x < hi) atomicAdd(&h[d.x - lo], 65536u);
        if (d.y >= lo && d.y < hi) atomicAdd(&h[d.y - lo], 65536u);
        if (d.z >= lo && d.z < hi) atomicAdd(&h[d.z - lo], 65536u);
        if (d.w >= lo && d.w < hi) atomicAdd(&h[d.w - lo], 65536u);
    }
    __syncthreads();
    int g0 = gp * 2;
    uint32* dst0 = scratch + ((size_t)(g0 * NSL + sl)) * RANGE;
    uint32* dst1 = scratch + ((size_t)((g0 + 1) * NSL + sl)) * RANGE;
    for (int i = threadIdx.x; i < RANGE; i += 512) dst0[i] = h[i];
    for (int i = threadIdx.x; i < RANGE; i += 512) dst1[i] = h[RANGE + i];
}

// ---------------- reduce per-block counts -> degrees + norms ----------------
__global__ void k_sumdeg(const uint32* __restrict__ scratch, int* __restrict__ deg_in,
                         float* __restrict__ n_src, float* __restrict__ n_dst) {
    int i = blockIdx.x * blockDim.x + threadIdx.x;
    if (i >= N_NODES) return;
    if (i == 0) n_src[N_NODES] = 0.f;   // gather sentinel
    int g = i / RANGE, r = i - g * RANGE;
    const uint32* base = scratch + (size_t)g * NSL * RANGE + r;
    uint32 so = 0, di = 0;
    for (int s = 0; s < NSL; s++) {
        uint32 v = base[(size_t)s * RANGE];
        so += v & 0xFFFFu;
        di += v >> 16;
    }
    deg_in[i] = (int)di;
    uint32 so1 = so < 1u ? 1u : so;
    uint32 di1 = di < 1u ? 1u : di;
    n_src[i] = rsqrtf((float)so1);
    n_dst[i] = rsqrtf((float)di1);
}

// ---------------- scan (3-pass) over deg_in -> row_ptr ----------------
__global__ void k_scan1(const int* __restrict__ deg_in, int* __restrict__ row_ptr,
                        int* __restrict__ blk_sums) {
    __shared__ int sh[SCAN_B];
    int i = blockIdx.x * SCAN_B + threadIdx.x;
    int v = (i < N_NODES) ? deg_in[i] : 0;
    sh[threadIdx.x] = v;
    __syncthreads();
    for (int o = 1; o < SCAN_B; o <<= 1) {
        int t = 0;
        if ((int)threadIdx.x >= o) t = sh[threadIdx.x - o];
        __syncthreads();
        sh[threadIdx.x] += t;
        __syncthreads();
    }
    if (i < N_NODES) row_ptr[i] = sh[threadIdx.x] - v;   // exclusive within block
    if (threadIdx.x == SCAN_B - 1) blk_sums[blockIdx.x] = sh[SCAN_B - 1];
}

__global__ void k_scan2(int* __restrict__ blk_sums) {
    if (threadIdx.x == 0 && blockIdx.x == 0) {
        int acc = 0;
        for (int b = 0; b < NB_SCAN; b++) { int v = blk_sums[b]; blk_sums[b] = acc; acc += v; }
        blk_sums[NB_SCAN] = acc;
    }
}

__global__ void k_scan3(const int* __restrict__ blk_sums, int* __restrict__ row_ptr) {
    int i = blockIdx.x * SCAN_B + threadIdx.x;
    if (i < N_NODES) row_ptr[i] += blk_sums[blockIdx.x];
    if (i == 0) row_ptr[N_NODES] = blk_sums[NB_SCAN];
}

// ---------------- per-(g,slice) cursor start offsets (in-place on scratch) ----------------
__global__ void k_offsets(uint32* __restrict__ scratch, const int* __restrict__ row_ptr) {
    int i = blockIdx.x * blockDim.x + threadIdx.x;
    if (i >= N_NODES) return;
    int g = i / RANGE, r = i - g * RANGE;
    uint32* base = scratch + (size_t)g * NSL * RANGE + r;
    uint32 run = (uint32)row_ptr[i];
    for (int s = 0; s < NSL; s++) {
        uint32 v = base[(size_t)s * RANGE];
        base[(size_t)s * RANGE] = run;
        run += v >> 16;
    }
}

// ---------------- phase B: atomic-free counting-sort fill ----------------
// 2 node-groups per block (100 KB LDS cursors, 512 threads) — same slice
// mapping as k_hist (stride NSL*512).
__global__ __launch_bounds__(512) void k_fill2(const int4* __restrict__ src4,
                                               const int4* __restrict__ dst4,
                                               const uint32* __restrict__ scratch,
                                               int* __restrict__ col) {
    __shared__ uint32 cur[2 * RANGE];   // 100 KB
    int gp = blockIdx.x & 3, sl = blockIdx.x >> 2;
    int lo = gp * 2 * RANGE, hi = lo + 2 * RANGE;
    int g0 = gp * 2;
    const uint32* base0 = scratch + ((size_t)(g0 * NSL + sl)) * RANGE;
    const uint32* base1 = scratch + ((size_t)((g0 + 1) * NSL + sl)) * RANGE;
    for (int i = threadIdx.x; i < RANGE; i += 512) cur[i] = base0[i];
    for (int i = threadIdx.x; i < RANGE; i += 512) cur[RANGE + i] = base1[i];
    __syncthreads();
    for (int t = sl * 512 + threadIdx.x; t < NVEC4; t += NSL * 512) {
        int4 s = src4[t], d = dst4[t];
        if (d.x >= lo && d.x < hi) { uint32 p = atomicAdd(&cur[d.x - lo], 1u); col[p] = s.x; }
        if (d.y >= lo && d.y < hi) { uint32 p = atomicAdd(&cur[d.y - lo], 1u); col[p] = s.y; }
        if (d.z >= lo && d.z < hi) { uint32 p = atomicAdd(&cur[d.z - lo], 1u); col[p] = s.z; }
        if (d.w >= lo && d.w < hi) { uint32 p = atomicAdd(&cur[d.w - lo], 1u); col[p] = s.w; }
    }
}

// ---------------- tiny weight-collapse GEMMs ----------------
__global__ void k_w01(const float* __restrict__ W0, const float* __restrict__ W1,
                      float* __restrict__ W01) {
    __shared__ float row[NHID];
    int r = blockIdx.x, c = threadIdx.x;   // 128 threads
    row[c] = W0[r * NHID + c];
    __syncthreads();
    float acc = 0.f;
    for (int k = 0; k < NHID; k++) acc += row[k] * W1[k * NHID + c];
    W01[r * NHID + c] = acc;
}

// also emits Wt: bf16, transposed [NCLASS][NFEAT] — B-operand for the MFMA GEMM
__global__ void k_wc(const float* __restrict__ W01, const float* __restrict__ W2,
                     float* __restrict__ Wc, ushort16* __restrict__ Wt) {
    __shared__ float row[NHID];
    int r = blockIdx.x, c = threadIdx.x;   // 64 threads
    row[c] = W01[r * NHID + c];
    row[c + 64] = W01[r * NHID + c + 64];
    __syncthreads();
    float acc = 0.f;
    for (int k = 0; k < NHID; k++) acc += row[k] * W2[k * NCLASS + c];
    Wc[r * NCLASS + c] = acc;
    Wt[(size_t)c * NFEAT + r] = f2b(acc);
}

// bv[0..63] = b0@W1@W2, bv[64..127] = b1@W2
__global__ void k_bv(const float* __restrict__ b0, const float* __restrict__ W1,
                     const float* __restrict__ b1, const float* __restrict__ W2,
                     float* __restrict__ bv) {
    __shared__ float tmp[NHID];
    int c = threadIdx.x;   // 64 threads
    for (int cc = c; cc < NHID; cc += 64) {
        float a = 0.f;
        for (int k = 0; k < NHID; k++) a += b0[k] * W1[k * NHID + cc];
        tmp[cc] = a;
    }
    __syncthreads();
    float a1 = 0.f, a2 = 0.f;
    for (int k = 0; k < NHID; k++) {
        float wv = W2[k * NCLASS + c];
        a1 += tmp[k] * wv;
        a2 += b1[k] * wv;
    }
    bv[c] = a1;
    bv[64 + c] = a2;
}

// ---------------- main GEMM: ys = (x @ Wc) * n_src  via MFMA, bf16 ----------------
// Rows are pre-scaled by n_src[row] so the aggregation passes do pure adds
// (no per-edge n_src gather). Row N_NODES is a zeroed sentinel for invalid
// edge slots. C/D (m89-verified): col=lane&15, row=(lane>>4)*4+reg.
__global__ __launch_bounds__(256) void k_gemm_y(const float* __restrict__ x,
                                                const ushort16* __restrict__ Wt,
                                                const float* __restrict__ n_src,
                                                ushort16* __restrict__ y) {
    int tid = threadIdx.x;
    int wid = tid >> 6, lane = tid & 63;
    int q = lane >> 4, r = lane & 15;
    int rowbase = blockIdx.x * 64 + wid * 16;
    int rowld = min(rowbase + r, N_NODES - 1);
    const float* xp = x + (size_t)rowld * NFEAT + q * 8;

    // issue all A loads up-front (16 dwordx4 in flight per lane)
    float4 alo[8], ahi[8];
#pragma unroll
    for (int kt = 0; kt < 8; kt++) {
        alo[kt] = *(const float4*)(xp + kt * 32);
        ahi[kt] = *(const float4*)(xp + kt * 32 + 4);
    }

    f32x4 acc0 = {0.f, 0.f, 0.f, 0.f};
    f32x4 acc1 = {0.f, 0.f, 0.f, 0.f};
    f32x4 acc2 = {0.f, 0.f, 0.f, 0.f};
    f32x4 acc3 = {0.f, 0.f, 0.f, 0.f};

#pragma unroll
    for (int kt = 0; kt < 8; kt++) {
        bf16x8 af;
        af[0] = (short)f2b(alo[kt].x); af[1] = (short)f2b(alo[kt].y);
        af[2] = (short)f2b(alo[kt].z); af[3] = (short)f2b(alo[kt].w);
        af[4] = (short)f2b(ahi[kt].x); af[5] = (short)f2b(ahi[kt].y);
        af[6] = (short)f2b(ahi[kt].z); af[7] = (short)f2b(ahi[kt].w);
        const int ko = kt * 32 + q * 8;
        bf16x8 b0 = *(const bf16x8*)(Wt + (size_t)(0 * 16 + r) * NFEAT + ko);
        bf16x8 b1 = *(const bf16x8*)(Wt + (size_t)(1 * 16 + r) * NFEAT + ko);
        bf16x8 b2 = *(const bf16x8*)(Wt + (size_t)(2 * 16 + r) * NFEAT + ko);
        bf16x8 b3 = *(const bf16x8*)(Wt + (size_t)(3 * 16 + r) * NFEAT + ko);
        acc0 = __builtin_amdgcn_mfma_f32_16x16x32_bf16(af, b0, acc0, 0, 0, 0);
        acc1 = __builtin_amdgcn_mfma_f32_16x16x32_bf16(af, b1, acc1, 0, 0, 0);
        acc2 = __builtin_amdgcn_mfma_f32_16x16x32_bf16(af, b2, acc2, 0, 0, 0);
        acc3 = __builtin_amdgcn_mfma_f32_16x16x32_bf16(af, b3, acc3, 0, 0, 0);
    }

    int srow0 = rowbase + q * 4;
#pragma unroll
    for (int i = 0; i < 4; i++) {
        int rr = srow0 + i;
        if (rr < N_NODES) {
            float ns = n_src[rr];
            ushort16* yp = y + (size_t)rr * NCLASS + r;
            yp[0]  = f2b(acc0[i] * ns);
            yp[16] = f2b(acc1[i] * ns);
            yp[32] = f2b(acc2[i] * ns);
            yp[48] = f2b(acc3[i] * ns);
        } else if (rr == N_NODES) {   // zero sentinel row
            ushort16* yp = y + (size_t)rr * NCLASS + r;
            yp[0] = 0; yp[16] = 0; yp[32] = 0; yp[48] = 0;
        }
    }
}

// ---------------- fused aggregation passes (pre-scaled rows, pure-add) ----------------
// Rows in `in` are pre-scaled by n_src[src]; invalid edge slots map to the
// zeroed sentinel row N_NODES -> pure packed-f32 adds, no mask, no ns gather.
// wsrc (scalar gather, L2-resident, sentinel=0): PASS1 = n_src (t1 = Â·1);
// PASS2 = t1s = n_src*t1 (t2 = Â·t1). Outputs of PASS1/2 are re-scaled by
// n_src[node] for the next pass's gather.
// PASS3: outf = softmax(acc*nd + t2*bv0 + t1*bv1 + b2) (f32 output).
template <int PASS>
__global__ __launch_bounds__(256) void k_agg(
        const int* __restrict__ row_ptr, const int* __restrict__ col,
        const float* __restrict__ wsrc,
        const float* __restrict__ n_src, const float* __restrict__ n_dst,
        const ushort16* __restrict__ in, ushort16* __restrict__ out,
        float* __restrict__ outf,
        float* __restrict__ tsave, float* __restrict__ tssave,
        const float* __restrict__ t1, const float* __restrict__ t2,
        const float* __restrict__ bv, const float* __restrict__ b2) {
    int wid = threadIdx.x >> 6, lane = threadIdx.x & 63;
    int node = blockIdx.x * 4 + wid;
    if (node > N_NODES) return;
    int g = lane >> 3, sub = lane & 7;

    if (node == N_NODES) {   // write zero sentinel row for the next pass
        if (PASS != 3) {
            if (g == 0) {
                uint4 z = {0u, 0u, 0u, 0u};
                *((uint4*)((char*)out + ((size_t)N_NODES << 7)) + sub) = z;
            }
            if (lane == 0) {
                tsave[N_NODES] = 0.f;
                if (PASS == 1) tssave[N_NODES] = 0.f;
            }
        }
        return;
    }

    int s = row_ptr[node], e = row_ptr[node + 1];
    const char* inb = (const char*)in;
    const char* wb  = (const char*)wsrc;
    uint32 subo = (uint32)sub << 4;

    f32x2 a0 = {0.f, 0.f}, a1 = {0.f, 0.f}, a2 = {0.f, 0.f}, a3 = {0.f, 0.f};
    float accs = 0.f;

#define CH(P)                                                                  \
    {                                                                          \
        int p_ = (P);                                                          \
        bool v_ = p_ < e;                                                      \
        int j_ = v_ ? col[p_] : N_NODES;                                       \
        uint32 fo_ = ((uint32)j_ << 7) + subo;                                 \
        uint4 u_ = *(const uint4*)(inb + fo_);                                 \
        if (PASS != 3) accs += *(const float*)(wb + ((uint32)j_ << 2));        \
        f32x2 q0; q0.x = blo(u_.x); q0.y = bhi(u_.x);                          \
        f32x2 q1; q1.x = blo(u_.y); q1.y = bhi(u_.y);                          \
        f32x2 q2; q2.x = blo(u_.z); q2.y = bhi(u_.z);                          \
        f32x2 q3; q3.x = blo(u_.w); q3.y = bhi(u_.w);                          \
        a0 += q0; a1 += q1; a2 += q2; a3 += q3;                                \
    }

    for (int base = s; base < e; base += 32) {
        CH(base + g)
        CH(base + 8 + g)
        CH(base + 16 + g)
        CH(base + 24 + g)
    }
#undef CH

    // reduce across the 8 edge-groups (lane bits 3..5)
#pragma unroll
    for (int off = 8; off <= 32; off <<= 1) {
        a0.x += __shfl_xor(a0.x, off, 64); a0.y += __shfl_xor(a0.y, off, 64);
        a1.x += __shfl_xor(a1.x, off, 64); a1.y += __shfl_xor(a1.y, off, 64);
        a2.x += __shfl_xor(a2.x, off, 64); a2.y += __shfl_xor(a2.y, off, 64);
        a3.x += __shfl_xor(a3.x, off, 64); a3.y += __shfl_xor(a3.y, off, 64);
        if (PASS != 3) accs += __shfl_xor(accs, off, 64);
    }

    float nd = n_dst[node];
    if (PASS == 3) {
        float t2n = t2[node], t1n = t1[node];
        const float* bvA = bv + sub * 8;
        const float* bvB = bv + 64 + sub * 8;
        const float* b2p = b2 + sub * 8;
        float v0 = a0.x * nd + t2n * bvA[0] + t1n * bvB[0] + b2p[0];
        float v1 = a0.y * nd + t2n * bvA[1] + t1n * bvB[1] + b2p[1];
        float v2 = a1.x * nd + t2n * bvA[2] + t1n * bvB[2] + b2p[2];
        float v3 = a1.y * nd + t2n * bvA[3] + t1n * bvB[3] + b2p[3];
        float v4 = a2.x * nd + t2n * bvA[4] + t1n * bvB[4] + b2p[4];
        float v5 = a2.y * nd + t2n * bvA[5] + t1n * bvB[5] + b2p[5];
        float v6 = a3.x * nd + t2n * bvA[6] + t1n * bvB[6] + b2p[6];
        float v7 = a3.y * nd + t2n * bvA[7] + t1n * bvB[7] + b2p[7];
        float m = fmaxf(fmaxf(fmaxf(v0, v1), fmaxf(v2, v3)),
                        fmaxf(fmaxf(v4, v5), fmaxf(v6, v7)));
#pragma unroll
        for (int off = 1; off <= 4; off <<= 1) m = fmaxf(m, __shfl_xor(m, off, 64));
        float e0 = __expf(v0 - m), e1 = __expf(v1 - m), e2 = __expf(v2 - m), e3 = __expf(v3 - m);
        float e4 = __expf(v4 - m), e5 = __expf(v5 - m), e6 = __expf(v6 - m), e7 = __expf(v7 - m);
        float sum = ((e0 + e1) + (e2 + e3)) + ((e4 + e5) + (e6 + e7));
#pragma unroll
        for (int off = 1; off <= 4; off <<= 1) sum += __shfl_xor(sum, off, 64);
        float r = 1.0f / sum;
        if (g == 0) {
            float4 o0 = {e0 * r, e1 * r, e2 * r, e3 * r};
            float4 o1 = {e4 * r, e5 * r, e6 * r, e7 * r};
            float4* op = (float4*)(outf + (size_t)node * NCLASS + sub * 8);
            op[0] = o0;
            op[1] = o1;
        }
    } else {
        if (g == 0) {
            float sc = nd * n_src[node];   // pre-scale for the next pass's gather
            uint32 w0 = pack2(a0.x * sc, a0.y * sc);
            uint32 w1 = pack2(a1.x * sc, a1.y * sc);
            uint32 w2 = pack2(a2.x * sc, a2.y * sc);
            uint32 w3 = pack2(a3.x * sc, a3.y * sc);
            uint4 w = {w0, w1, w2, w3};
            *((uint4*)((char*)out + ((size_t)node << 7)) + sub) = w;
        }
        if (lane == 0) {
            float T = accs * nd;
            tsave[node] = T;
            if (PASS == 1) tssave[node] = T * n_src[node];
        }
    }
}

extern "C" void kernel_launch(void* const* d_in, const int* in_sizes, int n_in,
                              void* d_out, int out_size, void* d_ws, size_t ws_size,
                              hipStream_t stream) {
    const float* x   = (const float*)d_in[0];
    const int*   src = (const int*)d_in[1];
    const int*   dst = (const int*)d_in[2];
    const float* W0  = (const float*)d_in[3];
    const float* b0  = (const float*)d_in[4];
    const float* W1  = (const float*)d_in[5];
    const float* b1  = (const float*)d_in[6];
    const float* W2  = (const float*)d_in[7];
    const float* b2  = (const float*)d_in[8];
    float* out = (float*)d_out;

    size_t off = 0;
    auto alloc = [&](size_t bytes) {
        void* p = (char*)d_ws + off;
        off = (off + bytes + 255) & ~(size_t)255;
        return p;
    };
    int*      deg_in   = (int*)alloc(N_NODES * 4);
    float*    n_src    = (float*)alloc((N_NODES + 1) * 4);   // +1 sentinel (=0)
    float*    n_dst    = (float*)alloc(N_NODES * 4);
    int*      row_ptr  = (int*)alloc((N_NODES + 1) * 4);
    int*      blk_sums = (int*)alloc((NB_SCAN + 1) * 4);
    int*      col      = (int*)alloc((size_t)N_EDGES * 4);
    uint32*   scratch  = (uint32*)alloc((size_t)8 * NSL * RANGE * 4);   // 25.6 MB
    float*    W01      = (float*)alloc(NFEAT * NHID * 4);
    float*    Wc       = (float*)alloc(NFEAT * NCLASS * 4);
    ushort16* Wt       = (ushort16*)alloc((size_t)NFEAT * NCLASS * 2);  // bf16, transposed
    float*    bv       = (float*)alloc(128 * 4);
    float*    t1       = (float*)alloc((N_NODES + 1) * 4);
    float*    t1s      = (float*)alloc((N_NODES + 1) * 4);   // n_src*t1, sentinel=0
    float*    t2       = (float*)alloc((N_NODES + 1) * 4);
    ushort16* bufB1    = (ushort16*)alloc((size_t)(N_NODES + 1) * NCLASS * 2);  // +sentinel row
    ushort16* bufB2    = (ushort16*)alloc((size_t)(N_NODES + 1) * NCLASS * 2);
    (void)ws_size; (void)in_sizes; (void)n_in; (void)out_size;

    const int TB = 256;
    const int NBn = (N_NODES + TB - 1) / TB;
    const int NW = (N_NODES + 3) / 4 + 1;   // +1 block: sentinel-row writer
    const int GP2 = 4 * NSL;                // 256 blocks (2 groups/block) for hist/fill

    k_hist<<<GP2, 512, 0, stream>>>((const int4*)src, (const int4*)dst, scratch);
    k_sumdeg<<<NBn, TB, 0, stream>>>(scratch, deg_in, n_src, n_dst);
    k_scan1<<<NB_SCAN, SCAN_B, 0, stream>>>(deg_in, row_ptr, blk_sums);
    k_scan2<<<1, 64, 0, stream>>>(blk_sums);
    k_scan3<<<NB_SCAN, SCAN_B, 0, stream>>>(blk_sums, row_ptr);
    k_offsets<<<NBn, TB, 0, stream>>>(scratch, row_ptr);
    k_fill2<<<GP2, 512, 0, stream>>>((const int4*)src, (const int4*)dst, scratch, col);

    k_w01<<<NFEAT, NHID, 0, stream>>>(W0, W1, W01);
    k_wc<<<NFEAT, NCLASS, 0, stream>>>(W01, W2, Wc, Wt);
    k_bv<<<1, NCLASS, 0, stream>>>(b0, W1, b1, W2, bv);

    // ys -> B1 (bf16, pre-scaled); Z1s -> B2 (+t1,t1s); Z2s -> B1 (+t2);
    // pass3: B1 -> softmax -> OUT (f32)
    k_gemm_y<<<(N_NODES + 64) / 64, 256, 0, stream>>>(x, Wt, n_src, bufB1);

    k_agg<1><<<NW, 256, 0, stream>>>(row_ptr, col, n_src, n_src, n_dst, bufB1, bufB2,
                                     nullptr, t1, t1s, nullptr, nullptr, nullptr, nullptr);
    k_agg<2><<<NW, 256, 0, stream>>>(row_ptr, col, t1s, n_src, n_dst, bufB2, bufB1,
                                     nullptr, t2, nullptr, nullptr, nullptr, nullptr, nullptr);
    k_agg<3><<<NW, 256, 0, stream>>>(row_ptr, col, nullptr, n_src, n_dst, bufB1, nullptr,
                                     out, nullptr, nullptr, t1, t2, bv, b2);
}